// Round 10
// baseline (441.147 us; speedup 1.0000x reference)
//
#include <hip/hip_runtime.h>

constexpr int N_NODES  = 100000;
constexpr int N_EDGES  = 1200000;
constexpr int N_GRAPHS = 1000;
constexpr int DIM      = 64;
constexpr int ODIM     = 32;
constexpr int MAXD     = 10;

constexpr int NR    = 4;          // src ranges (3.2MB bf16 window each, fits 4MB XCD L2)
constexpr int RDIV  = 25000;      // src / RDIV -> range id
constexpr int NBINS = N_NODES * NR;   // 400000

constexpr int SCAN_CHUNK = 1024;
constexpr int SCAN_NB    = (NBINS + SCAN_CHUNK - 1) / SCAN_CHUNK;  // 391

constexpr int NBKT     = 32;
constexpr int BPAD     = 32;
constexpr int LIST_PAD = N_NODES + NBKT * (BPAD - 1);  // 100992
constexpr int MV_BLK   = LIST_PAD / BPAD;              // 3156
constexpr int GATH_BLK = N_NODES / 32;                 // 3125

typedef unsigned long long ull;

// ---------------- bf16 helpers -------------------
__device__ __forceinline__ unsigned short f2bf(float f) {
    unsigned u = __float_as_uint(f);
    u = (u + 0x7fffu + ((u >> 16) & 1u)) >> 16;
    return (unsigned short)u;
}
__device__ __forceinline__ float bflo(int u) {
    return __uint_as_float((unsigned)u << 16);
}
__device__ __forceinline__ float bfhi(int u) {
    return __uint_as_float((unsigned)u & 0xffff0000u);
}
__device__ __forceinline__ unsigned packbf2(float lo, float hi) {
    return (unsigned)f2bf(lo) | ((unsigned)f2bf(hi) << 16);
}

// ---------------------------------------------------------------------------
// Init: cnt2 = 0, nodelist = -1, gcount = 0
// ---------------------------------------------------------------------------
__global__ void init_kernel(int* __restrict__ cnt2, int* __restrict__ gcount,
                            int* __restrict__ nodelist) {
    int i = blockIdx.x * 256 + threadIdx.x;
    if (i < NBINS) cnt2[i] = 0;
    if (i < LIST_PAD) nodelist[i] = -1;
    if (i < NBKT) gcount[i] = 0;
}

// ---------------------------------------------------------------------------
// Bin histogram over (dst, src-range): cnt2[4*dst + src/RDIV]++
// ---------------------------------------------------------------------------
__global__ void bin_hist_kernel(const int* __restrict__ src, const int* __restrict__ dst,
                                int* __restrict__ cnt2) {
    int e = blockIdx.x * blockDim.x + threadIdx.x;
    if (e < N_EDGES) {
        int key = dst[e] * NR + src[e] / RDIV;
        atomicAdd(&cnt2[key], 1);
    }
}

// ---------------------------------------------------------------------------
// Scan phase 1 over cnt2 (400K): per-block partials + bucket histogram
// ---------------------------------------------------------------------------
__global__ void scan_partial_kernel(const int* __restrict__ cnt2,
                                    int* __restrict__ partials,
                                    int* __restrict__ gcount) {
    __shared__ int red[256];
    __shared__ int lh[NBKT];
    int b = blockIdx.x, t = threadIdx.x;
    if (t < NBKT) lh[t] = 0;
    int base = b * SCAN_CHUNK + t * 4;
    int s = 0;
    if (base < NBINS) {
        int4 v = *reinterpret_cast<const int4*>(cnt2 + base);
        s = v.x + v.y + v.z + v.w;
    }
    red[t] = s;
    __syncthreads();
    for (int off = 128; off > 0; off >>= 1) {
        if (t < off) red[t] += red[t + off];
        __syncthreads();
    }
    if (base < NBINS) atomicAdd(&lh[min(s, NBKT - 1)], 1);
    __syncthreads();
    if (t < NBKT && lh[t]) atomicAdd(&gcount[t], lh[t]);
    if (t == 0) partials[b] = red[0];
}

// ---------------------------------------------------------------------------
// Scan phase 2 (single 512-thr block)
// ---------------------------------------------------------------------------
__global__ void scan_mid_kernel(const int* __restrict__ partials,
                                int* __restrict__ blockoff,
                                int* __restrict__ rowptr2,
                                const int* __restrict__ gcount,
                                int* __restrict__ gcur) {
    __shared__ int sh[512];
    int t = threadIdx.x;
    int v = (t < SCAN_NB) ? partials[t] : 0;
    sh[t] = v;
    __syncthreads();
    for (int off = 1; off < 512; off <<= 1) {
        int u = (t >= off) ? sh[t - off] : 0;
        __syncthreads();
        sh[t] += u;
        __syncthreads();
    }
    if (t < SCAN_NB) blockoff[t] = sh[t] - v;
    if (t == 0) {
        rowptr2[NBINS] = N_EDGES;
        int off = 0;
        for (int k = 0; k < NBKT; ++k) {
            gcur[k] = off;
            off += (gcount[k] + BPAD - 1) & ~(BPAD - 1);
        }
    }
}

// ---------------------------------------------------------------------------
// Scan phase 3: rowptr2/cursor2 writeout + bucket scatter
// ---------------------------------------------------------------------------
__global__ void scan_final_kernel(const int* __restrict__ cnt2,
                                  const int* __restrict__ blockoff,
                                  int* __restrict__ rowptr2,
                                  int* __restrict__ cursor2,
                                  int* __restrict__ gcur,
                                  int* __restrict__ nodelist) {
    __shared__ int sh[256];
    __shared__ int lh[NBKT], lbase[NBKT], lh2[NBKT];
    int b = blockIdx.x, t = threadIdx.x;
    if (t < NBKT) { lh[t] = 0; lh2[t] = 0; }
    int base = b * SCAN_CHUNK + t * 4;
    int4 v = make_int4(0, 0, 0, 0);
    if (base < NBINS) v = *reinterpret_cast<const int4*>(cnt2 + base);
    int s = v.x + v.y + v.z + v.w;
    sh[t] = s;
    __syncthreads();
    for (int off = 1; off < 256; off <<= 1) {
        int u = (t >= off) ? sh[t - off] : 0;
        __syncthreads();
        sh[t] += u;
        __syncthreads();
    }
    int k = min(s, NBKT - 1);
    if (base < NBINS) {
        int p0 = sh[t] - s + blockoff[b];
        int p1 = p0 + v.x, p2 = p1 + v.y, p3 = p2 + v.z;
        int4 pr = make_int4(p0, p1, p2, p3);
        *reinterpret_cast<int4*>(rowptr2 + base) = pr;
        *reinterpret_cast<int4*>(cursor2 + base) = pr;
        atomicAdd(&lh[k], 1);
    }
    __syncthreads();
    if (t < NBKT && lh[t]) lbase[t] = atomicAdd(&gcur[t], lh[t]);
    __syncthreads();
    if (base < NBINS) {
        int r = atomicAdd(&lh2[k], 1);
        nodelist[lbase[k] + r] = base >> 2;   // node id
    }
}

// ---------------------------------------------------------------------------
// Bin edges: csr[pos] = src (nt store: bypass L2 partial-dirty-line writeback)
// ---------------------------------------------------------------------------
__global__ void fill_csr_kernel(const int* __restrict__ src, const int* __restrict__ dst,
                                int* __restrict__ cursor2, int* __restrict__ csr) {
    int e = blockIdx.x * blockDim.x + threadIdx.x;
    if (e < N_EDGES) {
        int s = src[e];
        int key = dst[e] * NR + s / RDIV;
        int p = atomicAdd(&cursor2[key], 1);
        __builtin_nontemporal_store(s, &csr[p]);
    }
}

// ---------------------------------------------------------------------------
// f32 -> bf16 row conversion
// ---------------------------------------------------------------------------
__global__ void f32_to_bf16_kernel(const float* __restrict__ in,
                                   unsigned short* __restrict__ out) {
    int i = (blockIdx.x * blockDim.x + threadIdx.x) * 4;
    if (i < N_NODES * DIM) {
        float4 v = *reinterpret_cast<const float4*>(in + i);
        ushort4 o;
        o.x = f2bf(v.x); o.y = f2bf(v.y); o.z = f2bf(v.z); o.w = f2bf(v.w);
        *reinterpret_cast<ushort4*>(out + i) = o;
    }
}

// ---------------------------------------------------------------------------
// Phase gather with L2-protected window:
//   x-table reads  -> normal (cached; 3.2MB window stays resident in L2)
//   csr reads      -> NON-TEMPORAL (streaming, don't evict window)
//   hpart RMW      -> NON-TEMPORAL (streaming, don't evict window)
// ---------------------------------------------------------------------------
__global__ __launch_bounds__(256) void conv_gather_kernel(
        const unsigned short* __restrict__ xtab,
        const int* __restrict__ rowptr2,
        const int* __restrict__ csr,
        unsigned short* __restrict__ hpart,
        int r, int first) {
    int node = blockIdx.x * 32 + (threadIdx.x >> 3);
    int q = threadIdx.x & 7;
    int j = node * NR + r;
    int beg = rowptr2[j];
    int end = rowptr2[j + 1];

    float hs[8];
#pragma unroll
    for (int i = 0; i < 8; ++i) hs[i] = 0.f;

#define BFACC(a) \
    hs[0] += bflo(a.x); hs[1] += bfhi(a.x); \
    hs[2] += bflo(a.y); hs[3] += bfhi(a.y); \
    hs[4] += bflo(a.z); hs[5] += bfhi(a.z); \
    hs[6] += bflo(a.w); hs[7] += bfhi(a.w);

    int e = beg;
    for (; e + 4 <= end; e += 4) {
        int s0 = __builtin_nontemporal_load(csr + e + 0);
        int s1 = __builtin_nontemporal_load(csr + e + 1);
        int s2 = __builtin_nontemporal_load(csr + e + 2);
        int s3 = __builtin_nontemporal_load(csr + e + 3);
        int4 a0 = *reinterpret_cast<const int4*>(xtab + (size_t)s0 * DIM + q * 8);
        int4 a1 = *reinterpret_cast<const int4*>(xtab + (size_t)s1 * DIM + q * 8);
        int4 a2 = *reinterpret_cast<const int4*>(xtab + (size_t)s2 * DIM + q * 8);
        int4 a3 = *reinterpret_cast<const int4*>(xtab + (size_t)s3 * DIM + q * 8);
        BFACC(a0) BFACC(a1) BFACC(a2) BFACC(a3)
    }
    for (; e < end; ++e) {
        int s = __builtin_nontemporal_load(csr + e);
        int4 a = *reinterpret_cast<const int4*>(xtab + (size_t)s * DIM + q * 8);
        BFACC(a)
    }
#undef BFACC

    size_t off = (size_t)node * DIM + q * 8;
    ull* hp = reinterpret_cast<ull*>(hpart + off);
    if (!first) {
        ull u0 = __builtin_nontemporal_load(hp);
        ull u1 = __builtin_nontemporal_load(hp + 1);
        hs[0] += __uint_as_float((unsigned)(u0 & 0xffffu) << 16);
        hs[1] += __uint_as_float((unsigned)u0 & 0xffff0000u);
        hs[2] += __uint_as_float((unsigned)((u0 >> 32) & 0xffffu) << 16);
        hs[3] += __uint_as_float((unsigned)(u0 >> 32) & 0xffff0000u);
        hs[4] += __uint_as_float((unsigned)(u1 & 0xffffu) << 16);
        hs[5] += __uint_as_float((unsigned)u1 & 0xffff0000u);
        hs[6] += __uint_as_float((unsigned)((u1 >> 32) & 0xffffu) << 16);
        hs[7] += __uint_as_float((unsigned)(u1 >> 32) & 0xffff0000u);
    }
    ull o0 = (ull)packbf2(hs[0], hs[1]) | ((ull)packbf2(hs[2], hs[3]) << 32);
    ull o1 = (ull)packbf2(hs[4], hs[5]) | ((ull)packbf2(hs[6], hs[7]) << 32);
    __builtin_nontemporal_store(o0, hp);
    __builtin_nontemporal_store(o1, hp + 1);
}

// ---------------------------------------------------------------------------
// Bucketed matvec: 32 nodes/block (uniform weight index)
// ---------------------------------------------------------------------------
template <int OUTMODE>
__global__ __launch_bounds__(256) void conv_mv_kernel(
        const unsigned short* __restrict__ xtab,
        const unsigned short* __restrict__ hpart,
        const int* __restrict__ rowptr2,
        const int* __restrict__ nodelist,
        const float* __restrict__ Wl,
        const float* __restrict__ bl,
        const float* __restrict__ Wr,
        float* __restrict__ outf,
        unsigned short* __restrict__ outb) {
    __shared__ float lds_h[BPAD][DIM + 4];
    __shared__ float lds_x[BPAD][DIM + 4];
    __shared__ int s_node[BPAD];
    __shared__ int s_d0;

    int base = blockIdx.x * BPAD;
    int node0 = nodelist[base];
    if (node0 < 0) return;

    int grp = threadIdx.x >> 3;
    int q   = threadIdx.x & 7;
    int node = nodelist[base + grp];
    bool valid = (node >= 0);

    if (threadIdx.x == 0)
        s_d0 = min(rowptr2[node0 * NR + NR] - rowptr2[node0 * NR], MAXD);
    if (q == 0) s_node[grp] = node;

    float hv[8], xv[8];
    if (valid) {
        int4 a = *reinterpret_cast<const int4*>(hpart + (size_t)node * DIM + q * 8);
        hv[0] = bflo(a.x); hv[1] = bfhi(a.x);
        hv[2] = bflo(a.y); hv[3] = bfhi(a.y);
        hv[4] = bflo(a.z); hv[5] = bfhi(a.z);
        hv[6] = bflo(a.w); hv[7] = bfhi(a.w);
        int4 b = *reinterpret_cast<const int4*>(xtab + (size_t)node * DIM + q * 8);
        xv[0] = bflo(b.x); xv[1] = bfhi(b.x);
        xv[2] = bflo(b.y); xv[3] = bfhi(b.y);
        xv[4] = bflo(b.z); xv[5] = bfhi(b.z);
        xv[6] = bflo(b.w); xv[7] = bfhi(b.w);
    } else {
#pragma unroll
        for (int i = 0; i < 8; ++i) { hv[i] = 0.f; xv[i] = 0.f; }
    }

    *reinterpret_cast<float4*>(&lds_h[grp][q * 8 + 0]) = make_float4(hv[0], hv[1], hv[2], hv[3]);
    *reinterpret_cast<float4*>(&lds_h[grp][q * 8 + 4]) = make_float4(hv[4], hv[5], hv[6], hv[7]);
    *reinterpret_cast<float4*>(&lds_x[grp][q * 8 + 0]) = make_float4(xv[0], xv[1], xv[2], xv[3]);
    *reinterpret_cast<float4*>(&lds_x[grp][q * 8 + 4]) = make_float4(xv[4], xv[5], xv[6], xv[7]);
    __syncthreads();

    int mgrp = threadIdx.x >> 4;
    int mq   = threadIdx.x & 15;
    int d0 = s_d0;
    const float* wl = Wl + (size_t)d0 * DIM * DIM + mq * 4;
    const float* wr = Wr + (size_t)d0 * DIM * DIM + mq * 4;
    float4 accA = *reinterpret_cast<const float4*>(bl + d0 * DIM + mq * 4);
    float4 accB = accA;

#pragma unroll 8
    for (int i = 0; i < DIM; ++i) {
        float4 wlv = *reinterpret_cast<const float4*>(wl + i * DIM);
        float4 wrv = *reinterpret_cast<const float4*>(wr + i * DIM);
        float hA = lds_h[mgrp][i],      xA = lds_x[mgrp][i];
        float hB = lds_h[mgrp + 16][i], xB = lds_x[mgrp + 16][i];
        accA.x += hA * wlv.x + xA * wrv.x;
        accA.y += hA * wlv.y + xA * wrv.y;
        accA.z += hA * wlv.z + xA * wrv.z;
        accA.w += hA * wlv.w + xA * wrv.w;
        accB.x += hB * wlv.x + xB * wrv.x;
        accB.y += hB * wlv.y + xB * wrv.y;
        accB.z += hB * wlv.z + xB * wrv.z;
        accB.w += hB * wlv.w + xB * wrv.w;
    }

    int nodeA = s_node[mgrp];
    int nodeB = s_node[mgrp + 16];
    if (OUTMODE == 0) {
        if (nodeA >= 0)
            *reinterpret_cast<float4*>(outf + (size_t)nodeA * DIM + mq * 4) = accA;
        if (nodeB >= 0)
            *reinterpret_cast<float4*>(outf + (size_t)nodeB * DIM + mq * 4) = accB;
    } else {
        if (nodeA >= 0) {
            ushort4 o;
            o.x = f2bf(fmaxf(accA.x, 0.f)); o.y = f2bf(fmaxf(accA.y, 0.f));
            o.z = f2bf(fmaxf(accA.z, 0.f)); o.w = f2bf(fmaxf(accA.w, 0.f));
            *reinterpret_cast<ushort4*>(outb + (size_t)nodeA * DIM + mq * 4) = o;
        }
        if (nodeB >= 0) {
            ushort4 o;
            o.x = f2bf(fmaxf(accB.x, 0.f)); o.y = f2bf(fmaxf(accB.y, 0.f));
            o.z = f2bf(fmaxf(accB.z, 0.f)); o.w = f2bf(fmaxf(accB.w, 0.f));
            *reinterpret_cast<ushort4*>(outb + (size_t)nodeB * DIM + mq * 4) = o;
        }
    }
}

// ---------------------------------------------------------------------------
// Fused global_add_pool(relu(emb)) + MLP head; one block per graph.
// ---------------------------------------------------------------------------
__global__ void pool_head_kernel(const float* __restrict__ emb,
                                 const int* __restrict__ batch,
                                 const float* __restrict__ W1,
                                 const float* __restrict__ b1,
                                 const float* __restrict__ W2,
                                 const float* __restrict__ b2,
                                 float* __restrict__ pred) {
    __shared__ float red[4][DIM];
    __shared__ float garr[DIM];
    __shared__ float hid[DIM];
    int gi = blockIdx.x;
    int w = threadIdx.x >> 6;
    int lane = threadIdx.x & 63;

    int lo = 0, hi = N_NODES;
    while (lo < hi) { int mid = (lo + hi) >> 1; if (batch[mid] < gi) lo = mid + 1; else hi = mid; }
    int beg = lo;
    hi = N_NODES;
    while (lo < hi) { int mid = (lo + hi) >> 1; if (batch[mid] < gi + 1) lo = mid + 1; else hi = mid; }
    int end = lo;

    float acc = 0.f;
    for (int n = beg + w; n < end; n += 4)
        acc += fmaxf(emb[(size_t)n * DIM + lane], 0.f);
    red[w][lane] = acc;
    __syncthreads();
    if (w == 0)
        garr[lane] = red[0][lane] + red[1][lane] + red[2][lane] + red[3][lane];
    __syncthreads();

    if (threadIdx.x < DIM) {
        int o = threadIdx.x;
        float a = b1[o];
#pragma unroll 8
        for (int i = 0; i < DIM; ++i) a += garr[i] * W1[i * DIM + o];
        hid[o] = a;
    }
    __syncthreads();
    if (threadIdx.x < ODIM) {
        int o = threadIdx.x;
        float p = b2[o];
#pragma unroll 8
        for (int i = 0; i < DIM; ++i) p += hid[i] * W2[i * ODIM + o];
        pred[(size_t)gi * ODIM + o] = p;
    }
}

extern "C" void kernel_launch(void* const* d_in, const int* in_sizes, int n_in,
                              void* d_out, int out_size, void* d_ws, size_t ws_size,
                              hipStream_t stream) {
    const float* x    = (const float*)d_in[0];
    const int* eidx   = (const int*)d_in[1];
    const int* src    = eidx;
    const int* dst    = eidx + N_EDGES;
    const int* batch  = (const int*)d_in[2];
    const float* Wl1  = (const float*)d_in[4];
    const float* bl1  = (const float*)d_in[5];
    const float* Wr1  = (const float*)d_in[6];
    const float* Wl2  = (const float*)d_in[7];
    const float* bl2  = (const float*)d_in[8];
    const float* Wr2  = (const float*)d_in[9];
    const float* W1   = (const float*)d_in[10];
    const float* b1   = (const float*)d_in[11];
    const float* W2   = (const float*)d_in[12];
    const float* b2   = (const float*)d_in[13];

    float* emb  = (float*)d_out;                          // [N_NODES, 64]
    float* pred = (float*)d_out + (size_t)N_NODES * DIM;  // [N_GRAPHS, 32]

    // Workspace (int region sizes all multiples of 4 -> 16B alignment kept)
    int* cnt2     = (int*)d_ws;                  // [400000]
    int* rowptr2  = cnt2 + NBINS;                // [400004]
    int* cursor2  = rowptr2 + NBINS + 4;         // [400000]
    int* csr      = cursor2 + NBINS;             // [1200000]
    int* partials = csr + N_EDGES;               // [400]
    int* blockoff = partials + 400;              // [400]
    int* gcount   = blockoff + 400;              // [32]
    int* gcur     = gcount + NBKT;               // [32]
    int* nodelist = gcur + NBKT;                 // [100992]
    unsigned short* xbf   = (unsigned short*)(nodelist + LIST_PAD);  // [N*64]
    unsigned short* hbf   = xbf + (size_t)N_NODES * DIM;             // [N*64]
    unsigned short* hpart = hbf + (size_t)N_NODES * DIM;             // [N*64]

    init_kernel<<<(NBINS + 255) / 256, 256, 0, stream>>>(cnt2, gcount, nodelist);
    bin_hist_kernel<<<(N_EDGES + 255) / 256, 256, 0, stream>>>(src, dst, cnt2);
    scan_partial_kernel<<<SCAN_NB, 256, 0, stream>>>(cnt2, partials, gcount);
    scan_mid_kernel<<<1, 512, 0, stream>>>(partials, blockoff, rowptr2, gcount, gcur);
    scan_final_kernel<<<SCAN_NB, 256, 0, stream>>>(cnt2, blockoff, rowptr2, cursor2,
                                                   gcur, nodelist);
    fill_csr_kernel<<<(N_EDGES + 255) / 256, 256, 0, stream>>>(src, dst, cursor2, csr);
    f32_to_bf16_kernel<<<(N_NODES * DIM / 4 + 255) / 256, 256, 0, stream>>>(x, xbf);

    // conv1: 4 L2-windowed gather phases (nt streaming) -> hpart, then matvec
    for (int r = 0; r < NR; ++r)
        conv_gather_kernel<<<GATH_BLK, 256, 0, stream>>>(xbf, rowptr2, csr, hpart,
                                                         r, r == 0);
    conv_mv_kernel<1><<<MV_BLK, 256, 0, stream>>>(xbf, hpart, rowptr2, nodelist,
                                                  Wl1, bl1, Wr1, nullptr, hbf);
    // conv2: same over hbf -> emb
    for (int r = 0; r < NR; ++r)
        conv_gather_kernel<<<GATH_BLK, 256, 0, stream>>>(hbf, rowptr2, csr, hpart,
                                                         r, r == 0);
    conv_mv_kernel<0><<<MV_BLK, 256, 0, stream>>>(hbf, hpart, rowptr2, nodelist,
                                                  Wl2, bl2, Wr2, emb, nullptr);
    // fused pool + head
    pool_head_kernel<<<N_GRAPHS, 256, 0, stream>>>(emb, batch, W1, b1, W2, b2, pred);
}

// Round 11
// 247.512 us; speedup vs baseline: 1.7823x; 1.7823x over previous
//
#include <hip/hip_runtime.h>

constexpr int N_NODES  = 100000;
constexpr int N_EDGES  = 1200000;
constexpr int N_GRAPHS = 1000;
constexpr int DIM      = 64;
constexpr int ODIM     = 32;
constexpr int MAXD     = 10;

// coarse binning
constexpr int NPB   = 512;                      // nodes per coarse bucket (dst>>9)
constexpr int NBUK  = (N_NODES + NPB - 1) / NPB;  // 196
constexpr int CAP   = 8192;                     // pairs capacity/bucket (mean 6144, 26 sigma)
constexpr int EPB   = 4096;                     // edges per pass1 block
constexpr int P1_NB = (N_EDGES + EPB - 1) / EPB;  // 293

// degree-ordering buckets for conv
constexpr int NBKT     = 32;
constexpr int BPAD     = 32;
constexpr int LIST_PAD = N_NODES + NBKT * (BPAD - 1);  // 100992
constexpr int CONV_BLK = LIST_PAD / BPAD;              // 3156

// ---------------- bf16 helpers -------------------
__device__ __forceinline__ unsigned short f2bf(float f) {
    unsigned u = __float_as_uint(f);
    u = (u + 0x7fffu + ((u >> 16) & 1u)) >> 16;
    return (unsigned short)u;
}
__device__ __forceinline__ float bflo(int u) {
    return __uint_as_float((unsigned)u << 16);
}
__device__ __forceinline__ float bfhi(int u) {
    return __uint_as_float((unsigned)u & 0xffff0000u);
}

// ---------------------------------------------------------------------------
// Init: bucket cursors, gcount, nodelist
// ---------------------------------------------------------------------------
__global__ void init_kernel(int* __restrict__ bcur, int* __restrict__ gcount,
                            int* __restrict__ nodelist) {
    int i = blockIdx.x * 256 + threadIdx.x;
    if (i < LIST_PAD) nodelist[i] = -1;
    if (i < NBUK) bcur[i] = 0;
    if (i < NBKT) gcount[i] = 0;
}

// ---------------------------------------------------------------------------
// pass1: block counting-sort of EPB edges into NBUK coarse buckets, then
// bulk append per bucket (coalesced runs) into pairs[b*CAP + ...].
// pack = src | (dst&511)<<17
// ---------------------------------------------------------------------------
__global__ __launch_bounds__(256) void pass1_bin_kernel(const int* __restrict__ src,
                                                        const int* __restrict__ dst,
                                                        int* __restrict__ bcur,
                                                        int* __restrict__ pairs) {
    __shared__ int hist[NBUK];
    __shared__ int sexcl[NBUK];
    __shared__ int bbase[NBUK];
    __shared__ int sc[256];
    __shared__ int buf[EPB];
    __shared__ unsigned char bid[EPB];
    int t = threadIdx.x;
    for (int i = t; i < NBUK; i += 256) hist[i] = 0;
    __syncthreads();

    int e0 = blockIdx.x * EPB;
    int cnt = min(EPB, N_EDGES - e0);

    int pk[16], pb[16], pr[16];
#pragma unroll
    for (int k = 0; k < 16; ++k) {
        int j = t + k * 256;
        pb[k] = -1;
        if (j < cnt) {
            int s = src[e0 + j];
            int d = dst[e0 + j];
            int b = d >> 9;
            pb[k] = b;
            pk[k] = s | ((d & (NPB - 1)) << 17);
            pr[k] = atomicAdd(&hist[b], 1);
        }
    }
    __syncthreads();

    // exclusive scan of hist (NBUK<=256) + reserve global space per bucket
    int v = (t < NBUK) ? hist[t] : 0;
    sc[t] = v;
    __syncthreads();
    for (int off = 1; off < 256; off <<= 1) {
        int u = (t >= off) ? sc[t - off] : 0;
        __syncthreads();
        sc[t] += u;
        __syncthreads();
    }
    if (t < NBUK) {
        sexcl[t] = sc[t] - v;
        bbase[t] = v ? atomicAdd(&bcur[t], v) : 0;
    }
    __syncthreads();

    // scatter into bucket-sorted LDS buffer
#pragma unroll
    for (int k = 0; k < 16; ++k) {
        if (pb[k] >= 0) {
            int pos = sexcl[pb[k]] + pr[k];
            buf[pos] = pk[k];
            bid[pos] = (unsigned char)pb[k];
        }
    }
    __syncthreads();

    // coalesced copy-out: consecutive positions in a bucket -> consecutive global
#pragma unroll
    for (int k = 0; k < 16; ++k) {
        int j = t + k * 256;
        if (j < cnt) {
            int b = bid[j];
            pairs[(size_t)b * CAP + bbase[b] + (j - sexcl[b])] = buf[j];
        }
    }
}

// ---------------------------------------------------------------------------
// escan: exclusive scan of bucket counts -> ebase; rowptr[N]=E
// ---------------------------------------------------------------------------
__global__ void escan_kernel(const int* __restrict__ bcur, int* __restrict__ ebase,
                             int* __restrict__ rowptr) {
    __shared__ int sc[256];
    int t = threadIdx.x;
    int v = (t < NBUK) ? bcur[t] : 0;
    sc[t] = v;
    __syncthreads();
    for (int off = 1; off < 256; off <<= 1) {
        int u = (t >= off) ? sc[t - off] : 0;
        __syncthreads();
        sc[t] += u;
        __syncthreads();
    }
    if (t < NBUK) ebase[t] = sc[t] - v;
    if (t == NBUK - 1) ebase[NBUK] = sc[t];
    if (t == 0) rowptr[N_NODES] = N_EDGES;
}

// ---------------------------------------------------------------------------
// pass2: one block per coarse bucket (exclusive csr region -> one XCD):
//   LDS deg hist -> deg/rowptr coalesced writes -> LDS cursor scatter to csr.
//   Also accumulates the min(deg,31) histogram (gcount) for nodelist build.
// ---------------------------------------------------------------------------
__global__ __launch_bounds__(256) void pass2_kernel(const int* __restrict__ pairs,
                                                    const int* __restrict__ bcnt,
                                                    const int* __restrict__ ebase,
                                                    int* __restrict__ deg,
                                                    int* __restrict__ rowptr,
                                                    int* __restrict__ csr,
                                                    int* __restrict__ gcount) {
    __shared__ int dh[NPB];
    __shared__ int sc[256];
    __shared__ int gh[NBKT];
    int b = blockIdx.x, t = threadIdx.x;
    int nbeg = b * NPB;
    int nn = min(NPB, N_NODES - nbeg);
    int cnt = bcnt[b];
    int base = ebase[b];
    const int* reg = pairs + (size_t)b * CAP;

    for (int i = t; i < NPB; i += 256) dh[i] = 0;
    if (t < NBKT) gh[t] = 0;
    __syncthreads();

    for (int j = t; j < cnt; j += 256)
        atomicAdd(&dh[reg[j] >> 17], 1);
    __syncthreads();

    // exclusive scan over NPB=512 (2 elems/thread)
    int a0 = dh[2 * t];
    int a1 = dh[2 * t + 1];
    sc[t] = a0 + a1;
    __syncthreads();
    for (int off = 1; off < 256; off <<= 1) {
        int u = (t >= off) ? sc[t - off] : 0;
        __syncthreads();
        sc[t] += u;
        __syncthreads();
    }
    int e0 = sc[t] - (a0 + a1);    // exclusive prefix of element 2t
    int e1 = e0 + a0;              // exclusive prefix of element 2t+1
    int i0 = 2 * t, i1 = 2 * t + 1;
    if (i0 < nn) {
        deg[nbeg + i0] = a0;
        rowptr[nbeg + i0] = base + e0;
        atomicAdd(&gh[min(a0, NBKT - 1)], 1);
    }
    if (i1 < nn) {
        deg[nbeg + i1] = a1;
        rowptr[nbeg + i1] = base + e1;
        atomicAdd(&gh[min(a1, NBKT - 1)], 1);
    }
    __syncthreads();
    dh[i0] = e0;      // cursors = local exclusive offsets
    dh[i1] = e1;
    __syncthreads();

    for (int j = t; j < cnt; j += 256) {
        int p = reg[j];
        int r = atomicAdd(&dh[p >> 17], 1);
        csr[base + r] = p & 0x1FFFF;
    }
    __syncthreads();
    if (t < NBKT && gh[t]) atomicAdd(&gcount[t], gh[t]);
}

// ---------------------------------------------------------------------------
// gscan: bucket offsets for nodelist (ascending, BPAD-padded)
// ---------------------------------------------------------------------------
__global__ void gscan_kernel(const int* __restrict__ gcount, int* __restrict__ gcur) {
    if (threadIdx.x == 0) {
        int off = 0;
        for (int k = 0; k < NBKT; ++k) {
            gcur[k] = off;
            off += (gcount[k] + BPAD - 1) & ~(BPAD - 1);
        }
    }
}

// ---------------------------------------------------------------------------
// bucket scatter: nodes into degree-ordered nodelist
// ---------------------------------------------------------------------------
__global__ void bucket_scatter_kernel(const int* __restrict__ deg,
                                      int* __restrict__ gcur,
                                      int* __restrict__ nodelist) {
    __shared__ int lh[NBKT], lbase[NBKT];
    int t = threadIdx.x;
    if (t < NBKT) lh[t] = 0;
    __syncthreads();
    int i = blockIdx.x * 256 + t;
    int k = 0, r = 0;
    bool valid = (i < N_NODES);
    if (valid) {
        k = min(deg[i], NBKT - 1);
        r = atomicAdd(&lh[k], 1);
    }
    __syncthreads();
    if (t < NBKT && lh[t]) lbase[t] = atomicAdd(&gcur[t], lh[t]);
    __syncthreads();
    if (valid) nodelist[lbase[k] + r] = i;
}

// ---------------------------------------------------------------------------
// f32 -> bf16 row conversion
// ---------------------------------------------------------------------------
__global__ void f32_to_bf16_kernel(const float* __restrict__ in,
                                   unsigned short* __restrict__ out) {
    int i = (blockIdx.x * blockDim.x + threadIdx.x) * 4;
    if (i < N_NODES * DIM) {
        float4 v = *reinterpret_cast<const float4*>(in + i);
        ushort4 o;
        o.x = f2bf(v.x); o.y = f2bf(v.y); o.z = f2bf(v.z); o.w = f2bf(v.w);
        *reinterpret_cast<ushort4*>(out + i) = o;
    }
}

// ---------------------------------------------------------------------------
// Bucketed fused gather(bf16) + MFConv (R6-proven, 91us version).
// ---------------------------------------------------------------------------
template <int OUTMODE>
__global__ __launch_bounds__(256) void conv_bf16_kernel(
        const unsigned short* __restrict__ xbf,
        const int* __restrict__ rowptr,
        const int* __restrict__ csr,
        const int* __restrict__ nodelist,
        const float* __restrict__ Wl,
        const float* __restrict__ bl,
        const float* __restrict__ Wr,
        float* __restrict__ outf,
        unsigned short* __restrict__ outb) {
    __shared__ float lds_h[BPAD][DIM + 4];
    __shared__ float lds_x[BPAD][DIM + 4];
    __shared__ int s_node[BPAD];
    __shared__ int s_d0;

    int base = blockIdx.x * BPAD;
    int node0 = nodelist[base];
    if (node0 < 0) return;

    int grp = threadIdx.x >> 3;
    int q   = threadIdx.x & 7;
    int node = nodelist[base + grp];
    bool valid = (node >= 0);

    int beg = 0, end = 0;
    if (valid) { beg = rowptr[node]; end = rowptr[node + 1]; }

    if (threadIdx.x == 0) s_d0 = min(end - beg, MAXD);
    if (q == 0) s_node[grp] = node;

    float hs[8];
#pragma unroll
    for (int j = 0; j < 8; ++j) hs[j] = 0.f;

    int e = beg;
    for (; e + 8 <= end; e += 8) {
        int s0 = csr[e + 0], s1 = csr[e + 1], s2 = csr[e + 2], s3 = csr[e + 3];
        int s4 = csr[e + 4], s5 = csr[e + 5], s6 = csr[e + 6], s7 = csr[e + 7];
        int4 a0 = *reinterpret_cast<const int4*>(xbf + (size_t)s0 * DIM + q * 8);
        int4 a1 = *reinterpret_cast<const int4*>(xbf + (size_t)s1 * DIM + q * 8);
        int4 a2 = *reinterpret_cast<const int4*>(xbf + (size_t)s2 * DIM + q * 8);
        int4 a3 = *reinterpret_cast<const int4*>(xbf + (size_t)s3 * DIM + q * 8);
        int4 a4 = *reinterpret_cast<const int4*>(xbf + (size_t)s4 * DIM + q * 8);
        int4 a5 = *reinterpret_cast<const int4*>(xbf + (size_t)s5 * DIM + q * 8);
        int4 a6 = *reinterpret_cast<const int4*>(xbf + (size_t)s6 * DIM + q * 8);
        int4 a7 = *reinterpret_cast<const int4*>(xbf + (size_t)s7 * DIM + q * 8);
#define BFACC(a) \
        hs[0] += bflo(a.x); hs[1] += bfhi(a.x); \
        hs[2] += bflo(a.y); hs[3] += bfhi(a.y); \
        hs[4] += bflo(a.z); hs[5] += bfhi(a.z); \
        hs[6] += bflo(a.w); hs[7] += bfhi(a.w);
        BFACC(a0) BFACC(a1) BFACC(a2) BFACC(a3)
        BFACC(a4) BFACC(a5) BFACC(a6) BFACC(a7)
    }
    for (; e + 4 <= end; e += 4) {
        int s0 = csr[e + 0], s1 = csr[e + 1], s2 = csr[e + 2], s3 = csr[e + 3];
        int4 a0 = *reinterpret_cast<const int4*>(xbf + (size_t)s0 * DIM + q * 8);
        int4 a1 = *reinterpret_cast<const int4*>(xbf + (size_t)s1 * DIM + q * 8);
        int4 a2 = *reinterpret_cast<const int4*>(xbf + (size_t)s2 * DIM + q * 8);
        int4 a3 = *reinterpret_cast<const int4*>(xbf + (size_t)s3 * DIM + q * 8);
        BFACC(a0) BFACC(a1) BFACC(a2) BFACC(a3)
    }
    for (; e < end; ++e) {
        int s = csr[e];
        int4 a = *reinterpret_cast<const int4*>(xbf + (size_t)s * DIM + q * 8);
        BFACC(a)
    }
#undef BFACC

    float xv[8];
    if (valid) {
        int4 a = *reinterpret_cast<const int4*>(xbf + (size_t)node * DIM + q * 8);
        xv[0] = bflo(a.x); xv[1] = bfhi(a.x);
        xv[2] = bflo(a.y); xv[3] = bfhi(a.y);
        xv[4] = bflo(a.z); xv[5] = bfhi(a.z);
        xv[6] = bflo(a.w); xv[7] = bfhi(a.w);
    } else {
#pragma unroll
        for (int j = 0; j < 8; ++j) xv[j] = 0.f;
    }

    *reinterpret_cast<float4*>(&lds_h[grp][q * 8 + 0]) = make_float4(hs[0], hs[1], hs[2], hs[3]);
    *reinterpret_cast<float4*>(&lds_h[grp][q * 8 + 4]) = make_float4(hs[4], hs[5], hs[6], hs[7]);
    *reinterpret_cast<float4*>(&lds_x[grp][q * 8 + 0]) = make_float4(xv[0], xv[1], xv[2], xv[3]);
    *reinterpret_cast<float4*>(&lds_x[grp][q * 8 + 4]) = make_float4(xv[4], xv[5], xv[6], xv[7]);
    __syncthreads();

    int mgrp = threadIdx.x >> 4;
    int mq   = threadIdx.x & 15;
    int d0 = s_d0;
    const float* wl = Wl + (size_t)d0 * DIM * DIM + mq * 4;
    const float* wr = Wr + (size_t)d0 * DIM * DIM + mq * 4;
    float4 accA = *reinterpret_cast<const float4*>(bl + d0 * DIM + mq * 4);
    float4 accB = accA;

#pragma unroll 8
    for (int i = 0; i < DIM; ++i) {
        float4 wlv = *reinterpret_cast<const float4*>(wl + i * DIM);
        float4 wrv = *reinterpret_cast<const float4*>(wr + i * DIM);
        float hA = lds_h[mgrp][i],      xA = lds_x[mgrp][i];
        float hB = lds_h[mgrp + 16][i], xB = lds_x[mgrp + 16][i];
        accA.x += hA * wlv.x + xA * wrv.x;
        accA.y += hA * wlv.y + xA * wrv.y;
        accA.z += hA * wlv.z + xA * wrv.z;
        accA.w += hA * wlv.w + xA * wrv.w;
        accB.x += hB * wlv.x + xB * wrv.x;
        accB.y += hB * wlv.y + xB * wrv.y;
        accB.z += hB * wlv.z + xB * wrv.z;
        accB.w += hB * wlv.w + xB * wrv.w;
    }

    int nodeA = s_node[mgrp];
    int nodeB = s_node[mgrp + 16];
    if (OUTMODE == 0) {
        if (nodeA >= 0)
            *reinterpret_cast<float4*>(outf + (size_t)nodeA * DIM + mq * 4) = accA;
        if (nodeB >= 0)
            *reinterpret_cast<float4*>(outf + (size_t)nodeB * DIM + mq * 4) = accB;
    } else {
        if (nodeA >= 0) {
            ushort4 o;
            o.x = f2bf(fmaxf(accA.x, 0.f)); o.y = f2bf(fmaxf(accA.y, 0.f));
            o.z = f2bf(fmaxf(accA.z, 0.f)); o.w = f2bf(fmaxf(accA.w, 0.f));
            *reinterpret_cast<ushort4*>(outb + (size_t)nodeA * DIM + mq * 4) = o;
        }
        if (nodeB >= 0) {
            ushort4 o;
            o.x = f2bf(fmaxf(accB.x, 0.f)); o.y = f2bf(fmaxf(accB.y, 0.f));
            o.z = f2bf(fmaxf(accB.z, 0.f)); o.w = f2bf(fmaxf(accB.w, 0.f));
            *reinterpret_cast<ushort4*>(outb + (size_t)nodeB * DIM + mq * 4) = o;
        }
    }
}

// ---------------------------------------------------------------------------
// Fused global_add_pool(relu(emb)) + MLP head; one block per graph.
// ---------------------------------------------------------------------------
__global__ void pool_head_kernel(const float* __restrict__ emb,
                                 const int* __restrict__ batch,
                                 const float* __restrict__ W1,
                                 const float* __restrict__ b1,
                                 const float* __restrict__ W2,
                                 const float* __restrict__ b2,
                                 float* __restrict__ pred) {
    __shared__ float red[4][DIM];
    __shared__ float garr[DIM];
    __shared__ float hid[DIM];
    int gi = blockIdx.x;
    int w = threadIdx.x >> 6;
    int lane = threadIdx.x & 63;

    int lo = 0, hi = N_NODES;
    while (lo < hi) { int mid = (lo + hi) >> 1; if (batch[mid] < gi) lo = mid + 1; else hi = mid; }
    int beg = lo;
    hi = N_NODES;
    while (lo < hi) { int mid = (lo + hi) >> 1; if (batch[mid] < gi + 1) lo = mid + 1; else hi = mid; }
    int end = lo;

    float acc = 0.f;
    for (int n = beg + w; n < end; n += 4)
        acc += fmaxf(emb[(size_t)n * DIM + lane], 0.f);
    red[w][lane] = acc;
    __syncthreads();
    if (w == 0)
        garr[lane] = red[0][lane] + red[1][lane] + red[2][lane] + red[3][lane];
    __syncthreads();

    if (threadIdx.x < DIM) {
        int o = threadIdx.x;
        float a = b1[o];
#pragma unroll 8
        for (int i = 0; i < DIM; ++i) a += garr[i] * W1[i * DIM + o];
        hid[o] = a;
    }
    __syncthreads();
    if (threadIdx.x < ODIM) {
        int o = threadIdx.x;
        float p = b2[o];
#pragma unroll 8
        for (int i = 0; i < DIM; ++i) p += hid[i] * W2[i * ODIM + o];
        pred[(size_t)gi * ODIM + o] = p;
    }
}

extern "C" void kernel_launch(void* const* d_in, const int* in_sizes, int n_in,
                              void* d_out, int out_size, void* d_ws, size_t ws_size,
                              hipStream_t stream) {
    const float* x    = (const float*)d_in[0];
    const int* eidx   = (const int*)d_in[1];
    const int* src    = eidx;
    const int* dst    = eidx + N_EDGES;
    const int* batch  = (const int*)d_in[2];
    const float* Wl1  = (const float*)d_in[4];
    const float* bl1  = (const float*)d_in[5];
    const float* Wr1  = (const float*)d_in[6];
    const float* Wl2  = (const float*)d_in[7];
    const float* bl2  = (const float*)d_in[8];
    const float* Wr2  = (const float*)d_in[9];
    const float* W1   = (const float*)d_in[10];
    const float* b1   = (const float*)d_in[11];
    const float* W2   = (const float*)d_in[12];
    const float* b2   = (const float*)d_in[13];

    float* emb  = (float*)d_out;                          // [N_NODES, 64]
    float* pred = (float*)d_out + (size_t)N_NODES * DIM;  // [N_GRAPHS, 32]

    // Workspace (int counts multiples of 4 -> 16B alignment kept)
    int* bcur     = (int*)d_ws;                  // [256]  (bucket cursors / counts)
    int* ebase    = bcur + 256;                  // [256]  (bucket edge bases)
    int* gcount   = ebase + 256;                 // [32]
    int* gcur     = gcount + NBKT;               // [32]
    int* deg      = gcur + NBKT;                 // [100000]
    int* rowptr   = deg + N_NODES;               // [100004]
    int* nodelist = rowptr + N_NODES + 4;        // [100992]
    int* csr      = nodelist + LIST_PAD;         // [1200000]
    int* pairs    = csr + N_EDGES;               // [196*8192 = 1605632]
    unsigned short* xbf = (unsigned short*)(pairs + NBUK * CAP);   // [N*64] bf16
    unsigned short* hbf = xbf + (size_t)N_NODES * DIM;             // [N*64] bf16

    init_kernel<<<(LIST_PAD + 255) / 256, 256, 0, stream>>>(bcur, gcount, nodelist);
    pass1_bin_kernel<<<P1_NB, 256, 0, stream>>>(src, dst, bcur, pairs);
    escan_kernel<<<1, 256, 0, stream>>>(bcur, ebase, rowptr);
    pass2_kernel<<<NBUK, 256, 0, stream>>>(pairs, bcur, ebase, deg, rowptr, csr, gcount);
    gscan_kernel<<<1, 64, 0, stream>>>(gcount, gcur);
    bucket_scatter_kernel<<<(N_NODES + 255) / 256, 256, 0, stream>>>(deg, gcur, nodelist);
    f32_to_bf16_kernel<<<(N_NODES * DIM / 4 + 255) / 256, 256, 0, stream>>>(x, xbf);

    // conv1: bf16 gather + matvec + relu -> hbf
    conv_bf16_kernel<1><<<CONV_BLK, 256, 0, stream>>>(xbf, rowptr, csr, nodelist,
                                                      Wl1, bl1, Wr1, nullptr, hbf);
    // conv2: bf16 gather + matvec -> emb (f32, pre-activation output)
    conv_bf16_kernel<0><<<CONV_BLK, 256, 0, stream>>>(hbf, rowptr, csr, nodelist,
                                                      Wl2, bl2, Wr2, emb, nullptr);
    // fused pool + head
    pool_head_kernel<<<N_GRAPHS, 256, 0, stream>>>(emb, batch, W1, b1, W2, b2, pred);
}

// Round 12
// 242.268 us; speedup vs baseline: 1.8209x; 1.0216x over previous
//
#include <hip/hip_runtime.h>

constexpr int N_NODES  = 100000;
constexpr int N_EDGES  = 1200000;
constexpr int N_GRAPHS = 1000;
constexpr int DIM      = 64;
constexpr int ODIM     = 32;
constexpr int MAXD     = 10;

// coarse binning (two-level CSR build, R11-proven)
constexpr int NPB   = 512;
constexpr int NBUK  = (N_NODES + NPB - 1) / NPB;  // 196
constexpr int CAP   = 8192;
constexpr int EPB   = 4096;
constexpr int P1_NB = (N_EDGES + EPB - 1) / EPB;  // 293

// degree-ordering buckets for conv
constexpr int NBKT     = 32;
constexpr int BPAD     = 32;
constexpr int LIST_PAD = N_NODES + NBKT * (BPAD - 1);  // 100992
constexpr int CONV_BLK = LIST_PAD / BPAD;              // 3156

// ---------------- bf16 helpers -------------------
__device__ __forceinline__ unsigned short f2bf(float f) {
    unsigned u = __float_as_uint(f);
    u = (u + 0x7fffu + ((u >> 16) & 1u)) >> 16;
    return (unsigned short)u;
}
__device__ __forceinline__ float bflo(int u) {
    return __uint_as_float((unsigned)u << 16);
}
__device__ __forceinline__ float bfhi(int u) {
    return __uint_as_float((unsigned)u & 0xffff0000u);
}

// ---------------- fp8 e4m3fn helpers (self-consistent encode/decode) -------
__device__ __forceinline__ unsigned f32_to_e4m3(float f) {
    unsigned u = __float_as_uint(f);
    unsigned s = (u >> 24) & 0x80u;
    float a = fabsf(f);
    if (a >= 448.f) return s | 0x7Eu;
    if (a < 0.015625f) {                        // < 2^-6 : denormal, RNE
        int di = __float2int_rn(a * 512.0f);    // units of 2^-9, in [0,8]
        return s | (unsigned)di;                // 8 == min normal, packs correctly
    }
    unsigned au = u & 0x7fffffffu;
    unsigned e = (au >> 23) - 127u + 7u;        // 1..15
    unsigned m = (au >> 20) & 7u;
    unsigned rest = au & 0xFFFFFu;
    unsigned guard = (rest >> 19) & 1u;
    unsigned sticky = ((rest & 0x7FFFFu) != 0u) ? 1u : 0u;
    unsigned code = (e << 3) | m;
    code += (guard & (sticky | (m & 1u)));      // RNE; carry flows into exp
    if (code > 0x7Eu) code = 0x7Eu;             // saturate (0x7F is NaN)
    return s | code;
}
__device__ __forceinline__ float e4m3_to_f32(unsigned b) {
    unsigned s = (b & 0x80u) << 24;
    unsigned exp4 = (b >> 3) & 0xFu;
    unsigned mant = b & 7u;
    float v;
    if (exp4 == 0) {
        v = (float)mant * 0.001953125f;         // 2^-9
    } else {
        v = __uint_as_float(((exp4 + 120u) << 23) | (mant << 20));
    }
    return __uint_as_float(__float_as_uint(v) | s);
}

// ---------------------------------------------------------------------------
// prep: fused init (bcur/gcount/nodelist) + x f32 -> fp8 e4m3 table
// 800000 threads: thread converts 8 elements
// ---------------------------------------------------------------------------
constexpr int PREP_THREADS = N_NODES * DIM / 8;   // 800000
__global__ void prep_kernel(const float* __restrict__ x,
                            unsigned char* __restrict__ xq,
                            int* __restrict__ bcur, int* __restrict__ gcount,
                            int* __restrict__ nodelist) {
    int i = blockIdx.x * 256 + threadIdx.x;
    if (i < LIST_PAD) nodelist[i] = -1;
    if (i < NBUK) bcur[i] = 0;
    if (i < NBKT) gcount[i] = 0;
    if (i < PREP_THREADS) {
        const float4 v0 = *reinterpret_cast<const float4*>(x + (size_t)i * 8);
        const float4 v1 = *reinterpret_cast<const float4*>(x + (size_t)i * 8 + 4);
        unsigned lo = f32_to_e4m3(v0.x) | (f32_to_e4m3(v0.y) << 8)
                    | (f32_to_e4m3(v0.z) << 16) | (f32_to_e4m3(v0.w) << 24);
        unsigned hi = f32_to_e4m3(v1.x) | (f32_to_e4m3(v1.y) << 8)
                    | (f32_to_e4m3(v1.z) << 16) | (f32_to_e4m3(v1.w) << 24);
        uint2 o; o.x = lo; o.y = hi;
        *reinterpret_cast<uint2*>(xq + (size_t)i * 8) = o;
    }
}

// ---------------------------------------------------------------------------
// pass1: block counting-sort of EPB edges into NBUK coarse buckets (R11)
// ---------------------------------------------------------------------------
__global__ __launch_bounds__(256) void pass1_bin_kernel(const int* __restrict__ src,
                                                        const int* __restrict__ dst,
                                                        int* __restrict__ bcur,
                                                        int* __restrict__ pairs) {
    __shared__ int hist[NBUK];
    __shared__ int sexcl[NBUK];
    __shared__ int bbase[NBUK];
    __shared__ int sc[256];
    __shared__ int buf[EPB];
    __shared__ unsigned char bid[EPB];
    int t = threadIdx.x;
    for (int i = t; i < NBUK; i += 256) hist[i] = 0;
    __syncthreads();

    int e0 = blockIdx.x * EPB;
    int cnt = min(EPB, N_EDGES - e0);

    int pk[16], pb[16], pr[16];
#pragma unroll
    for (int k = 0; k < 16; ++k) {
        int j = t + k * 256;
        pb[k] = -1;
        if (j < cnt) {
            int s = src[e0 + j];
            int d = dst[e0 + j];
            int b = d >> 9;
            pb[k] = b;
            pk[k] = s | ((d & (NPB - 1)) << 17);
            pr[k] = atomicAdd(&hist[b], 1);
        }
    }
    __syncthreads();

    int v = (t < NBUK) ? hist[t] : 0;
    sc[t] = v;
    __syncthreads();
    for (int off = 1; off < 256; off <<= 1) {
        int u = (t >= off) ? sc[t - off] : 0;
        __syncthreads();
        sc[t] += u;
        __syncthreads();
    }
    if (t < NBUK) {
        sexcl[t] = sc[t] - v;
        bbase[t] = v ? atomicAdd(&bcur[t], v) : 0;
    }
    __syncthreads();

#pragma unroll
    for (int k = 0; k < 16; ++k) {
        if (pb[k] >= 0) {
            int pos = sexcl[pb[k]] + pr[k];
            buf[pos] = pk[k];
            bid[pos] = (unsigned char)pb[k];
        }
    }
    __syncthreads();

#pragma unroll
    for (int k = 0; k < 16; ++k) {
        int j = t + k * 256;
        if (j < cnt) {
            int b = bid[j];
            pairs[(size_t)b * CAP + bbase[b] + (j - sexcl[b])] = buf[j];
        }
    }
}

// ---------------------------------------------------------------------------
// escan: exclusive scan of bucket counts -> ebase; rowptr[N]=E
// ---------------------------------------------------------------------------
__global__ void escan_kernel(const int* __restrict__ bcur, int* __restrict__ ebase,
                             int* __restrict__ rowptr) {
    __shared__ int sc[256];
    int t = threadIdx.x;
    int v = (t < NBUK) ? bcur[t] : 0;
    sc[t] = v;
    __syncthreads();
    for (int off = 1; off < 256; off <<= 1) {
        int u = (t >= off) ? sc[t - off] : 0;
        __syncthreads();
        sc[t] += u;
        __syncthreads();
    }
    if (t < NBUK) ebase[t] = sc[t] - v;
    if (t == NBUK - 1) ebase[NBUK] = sc[t];
    if (t == 0) rowptr[N_NODES] = N_EDGES;
}

// ---------------------------------------------------------------------------
// pass2: one block per coarse bucket: deg/rowptr writeout + csr scatter (R11)
// ---------------------------------------------------------------------------
__global__ __launch_bounds__(256) void pass2_kernel(const int* __restrict__ pairs,
                                                    const int* __restrict__ bcnt,
                                                    const int* __restrict__ ebase,
                                                    int* __restrict__ deg,
                                                    int* __restrict__ rowptr,
                                                    int* __restrict__ csr,
                                                    int* __restrict__ gcount) {
    __shared__ int dh[NPB];
    __shared__ int sc[256];
    __shared__ int gh[NBKT];
    int b = blockIdx.x, t = threadIdx.x;
    int nbeg = b * NPB;
    int nn = min(NPB, N_NODES - nbeg);
    int cnt = bcnt[b];
    int base = ebase[b];
    const int* reg = pairs + (size_t)b * CAP;

    for (int i = t; i < NPB; i += 256) dh[i] = 0;
    if (t < NBKT) gh[t] = 0;
    __syncthreads();

    for (int j = t; j < cnt; j += 256)
        atomicAdd(&dh[reg[j] >> 17], 1);
    __syncthreads();

    int a0 = dh[2 * t];
    int a1 = dh[2 * t + 1];
    sc[t] = a0 + a1;
    __syncthreads();
    for (int off = 1; off < 256; off <<= 1) {
        int u = (t >= off) ? sc[t - off] : 0;
        __syncthreads();
        sc[t] += u;
        __syncthreads();
    }
    int e0 = sc[t] - (a0 + a1);
    int e1 = e0 + a0;
    int i0 = 2 * t, i1 = 2 * t + 1;
    if (i0 < nn) {
        deg[nbeg + i0] = a0;
        rowptr[nbeg + i0] = base + e0;
        atomicAdd(&gh[min(a0, NBKT - 1)], 1);
    }
    if (i1 < nn) {
        deg[nbeg + i1] = a1;
        rowptr[nbeg + i1] = base + e1;
        atomicAdd(&gh[min(a1, NBKT - 1)], 1);
    }
    __syncthreads();
    dh[i0] = e0;
    dh[i1] = e1;
    __syncthreads();

    for (int j = t; j < cnt; j += 256) {
        int p = reg[j];
        int r = atomicAdd(&dh[p >> 17], 1);
        csr[base + r] = p & 0x1FFFF;
    }
    __syncthreads();
    if (t < NBKT && gh[t]) atomicAdd(&gcount[t], gh[t]);
}

// ---------------------------------------------------------------------------
// gscan + bucket scatter (R11)
// ---------------------------------------------------------------------------
__global__ void gscan_kernel(const int* __restrict__ gcount, int* __restrict__ gcur) {
    if (threadIdx.x == 0) {
        int off = 0;
        for (int k = 0; k < NBKT; ++k) {
            gcur[k] = off;
            off += (gcount[k] + BPAD - 1) & ~(BPAD - 1);
        }
    }
}

__global__ void bucket_scatter_kernel(const int* __restrict__ deg,
                                      int* __restrict__ gcur,
                                      int* __restrict__ nodelist) {
    __shared__ int lh[NBKT], lbase[NBKT];
    int t = threadIdx.x;
    if (t < NBKT) lh[t] = 0;
    __syncthreads();
    int i = blockIdx.x * 256 + t;
    int k = 0, r = 0;
    bool valid = (i < N_NODES);
    if (valid) {
        k = min(deg[i], NBKT - 1);
        r = atomicAdd(&lh[k], 1);
    }
    __syncthreads();
    if (t < NBKT && lh[t]) lbase[t] = atomicAdd(&gcur[t], lh[t]);
    __syncthreads();
    if (valid) nodelist[lbase[k] + r] = i;
}

// ---------------------------------------------------------------------------
// conv1: fp8 gather (64B rows) + matvec + relu -> bf16 out
// ---------------------------------------------------------------------------
__global__ __launch_bounds__(256) void conv1_fp8_kernel(
        const unsigned char* __restrict__ xq,
        const int* __restrict__ rowptr,
        const int* __restrict__ csr,
        const int* __restrict__ nodelist,
        const float* __restrict__ Wl,
        const float* __restrict__ bl,
        const float* __restrict__ Wr,
        unsigned short* __restrict__ outb) {
    __shared__ float lds_h[BPAD][DIM + 4];
    __shared__ float lds_x[BPAD][DIM + 4];
    __shared__ int s_node[BPAD];
    __shared__ int s_d0;

    int base = blockIdx.x * BPAD;
    int node0 = nodelist[base];
    if (node0 < 0) return;

    int grp = threadIdx.x >> 3;
    int q   = threadIdx.x & 7;
    int node = nodelist[base + grp];
    bool valid = (node >= 0);

    int beg = 0, end = 0;
    if (valid) { beg = rowptr[node]; end = rowptr[node + 1]; }

    if (threadIdx.x == 0) s_d0 = min(end - beg, MAXD);
    if (q == 0) s_node[grp] = node;

    float hs[8];
#pragma unroll
    for (int j = 0; j < 8; ++j) hs[j] = 0.f;

#define QACC(a) { \
    hs[0] += e4m3_to_f32((a).x & 0xffu);        hs[1] += e4m3_to_f32(((a).x >> 8) & 0xffu); \
    hs[2] += e4m3_to_f32(((a).x >> 16) & 0xffu); hs[3] += e4m3_to_f32((a).x >> 24); \
    hs[4] += e4m3_to_f32((a).y & 0xffu);        hs[5] += e4m3_to_f32(((a).y >> 8) & 0xffu); \
    hs[6] += e4m3_to_f32(((a).y >> 16) & 0xffu); hs[7] += e4m3_to_f32((a).y >> 24); }

    int e = beg;
    for (; e + 8 <= end; e += 8) {
        int s0 = csr[e + 0], s1 = csr[e + 1], s2 = csr[e + 2], s3 = csr[e + 3];
        int s4 = csr[e + 4], s5 = csr[e + 5], s6 = csr[e + 6], s7 = csr[e + 7];
        uint2 a0 = *reinterpret_cast<const uint2*>(xq + (size_t)s0 * DIM + q * 8);
        uint2 a1 = *reinterpret_cast<const uint2*>(xq + (size_t)s1 * DIM + q * 8);
        uint2 a2 = *reinterpret_cast<const uint2*>(xq + (size_t)s2 * DIM + q * 8);
        uint2 a3 = *reinterpret_cast<const uint2*>(xq + (size_t)s3 * DIM + q * 8);
        uint2 a4 = *reinterpret_cast<const uint2*>(xq + (size_t)s4 * DIM + q * 8);
        uint2 a5 = *reinterpret_cast<const uint2*>(xq + (size_t)s5 * DIM + q * 8);
        uint2 a6 = *reinterpret_cast<const uint2*>(xq + (size_t)s6 * DIM + q * 8);
        uint2 a7 = *reinterpret_cast<const uint2*>(xq + (size_t)s7 * DIM + q * 8);
        QACC(a0) QACC(a1) QACC(a2) QACC(a3)
        QACC(a4) QACC(a5) QACC(a6) QACC(a7)
    }
    for (; e + 4 <= end; e += 4) {
        int s0 = csr[e + 0], s1 = csr[e + 1], s2 = csr[e + 2], s3 = csr[e + 3];
        uint2 a0 = *reinterpret_cast<const uint2*>(xq + (size_t)s0 * DIM + q * 8);
        uint2 a1 = *reinterpret_cast<const uint2*>(xq + (size_t)s1 * DIM + q * 8);
        uint2 a2 = *reinterpret_cast<const uint2*>(xq + (size_t)s2 * DIM + q * 8);
        uint2 a3 = *reinterpret_cast<const uint2*>(xq + (size_t)s3 * DIM + q * 8);
        QACC(a0) QACC(a1) QACC(a2) QACC(a3)
    }
    for (; e < end; ++e) {
        int s = csr[e];
        uint2 a = *reinterpret_cast<const uint2*>(xq + (size_t)s * DIM + q * 8);
        QACC(a)
    }
#undef QACC

    float xv[8];
    if (valid) {
        uint2 a = *reinterpret_cast<const uint2*>(xq + (size_t)node * DIM + q * 8);
        xv[0] = e4m3_to_f32(a.x & 0xffu);         xv[1] = e4m3_to_f32((a.x >> 8) & 0xffu);
        xv[2] = e4m3_to_f32((a.x >> 16) & 0xffu); xv[3] = e4m3_to_f32(a.x >> 24);
        xv[4] = e4m3_to_f32(a.y & 0xffu);         xv[5] = e4m3_to_f32((a.y >> 8) & 0xffu);
        xv[6] = e4m3_to_f32((a.y >> 16) & 0xffu); xv[7] = e4m3_to_f32(a.y >> 24);
    } else {
#pragma unroll
        for (int j = 0; j < 8; ++j) xv[j] = 0.f;
    }

    *reinterpret_cast<float4*>(&lds_h[grp][q * 8 + 0]) = make_float4(hs[0], hs[1], hs[2], hs[3]);
    *reinterpret_cast<float4*>(&lds_h[grp][q * 8 + 4]) = make_float4(hs[4], hs[5], hs[6], hs[7]);
    *reinterpret_cast<float4*>(&lds_x[grp][q * 8 + 0]) = make_float4(xv[0], xv[1], xv[2], xv[3]);
    *reinterpret_cast<float4*>(&lds_x[grp][q * 8 + 4]) = make_float4(xv[4], xv[5], xv[6], xv[7]);
    __syncthreads();

    int mgrp = threadIdx.x >> 4;
    int mq   = threadIdx.x & 15;
    int d0 = s_d0;
    const float* wl = Wl + (size_t)d0 * DIM * DIM + mq * 4;
    const float* wr = Wr + (size_t)d0 * DIM * DIM + mq * 4;
    float4 accA = *reinterpret_cast<const float4*>(bl + d0 * DIM + mq * 4);
    float4 accB = accA;

#pragma unroll 8
    for (int i = 0; i < DIM; ++i) {
        float4 wlv = *reinterpret_cast<const float4*>(wl + i * DIM);
        float4 wrv = *reinterpret_cast<const float4*>(wr + i * DIM);
        float hA = lds_h[mgrp][i],      xA = lds_x[mgrp][i];
        float hB = lds_h[mgrp + 16][i], xB = lds_x[mgrp + 16][i];
        accA.x += hA * wlv.x + xA * wrv.x;
        accA.y += hA * wlv.y + xA * wrv.y;
        accA.z += hA * wlv.z + xA * wrv.z;
        accA.w += hA * wlv.w + xA * wrv.w;
        accB.x += hB * wlv.x + xB * wrv.x;
        accB.y += hB * wlv.y + xB * wrv.y;
        accB.z += hB * wlv.z + xB * wrv.z;
        accB.w += hB * wlv.w + xB * wrv.w;
    }

    int nodeA = s_node[mgrp];
    int nodeB = s_node[mgrp + 16];
    if (nodeA >= 0) {
        ushort4 o;
        o.x = f2bf(fmaxf(accA.x, 0.f)); o.y = f2bf(fmaxf(accA.y, 0.f));
        o.z = f2bf(fmaxf(accA.z, 0.f)); o.w = f2bf(fmaxf(accA.w, 0.f));
        *reinterpret_cast<ushort4*>(outb + (size_t)nodeA * DIM + mq * 4) = o;
    }
    if (nodeB >= 0) {
        ushort4 o;
        o.x = f2bf(fmaxf(accB.x, 0.f)); o.y = f2bf(fmaxf(accB.y, 0.f));
        o.z = f2bf(fmaxf(accB.z, 0.f)); o.w = f2bf(fmaxf(accB.w, 0.f));
        *reinterpret_cast<ushort4*>(outb + (size_t)nodeB * DIM + mq * 4) = o;
    }
}

// ---------------------------------------------------------------------------
// conv2: bf16 gather + matvec -> f32 emb (R11-proven)
// ---------------------------------------------------------------------------
__global__ __launch_bounds__(256) void conv2_bf16_kernel(
        const unsigned short* __restrict__ xbf,
        const int* __restrict__ rowptr,
        const int* __restrict__ csr,
        const int* __restrict__ nodelist,
        const float* __restrict__ Wl,
        const float* __restrict__ bl,
        const float* __restrict__ Wr,
        float* __restrict__ outf) {
    __shared__ float lds_h[BPAD][DIM + 4];
    __shared__ float lds_x[BPAD][DIM + 4];
    __shared__ int s_node[BPAD];
    __shared__ int s_d0;

    int base = blockIdx.x * BPAD;
    int node0 = nodelist[base];
    if (node0 < 0) return;

    int grp = threadIdx.x >> 3;
    int q   = threadIdx.x & 7;
    int node = nodelist[base + grp];
    bool valid = (node >= 0);

    int beg = 0, end = 0;
    if (valid) { beg = rowptr[node]; end = rowptr[node + 1]; }

    if (threadIdx.x == 0) s_d0 = min(end - beg, MAXD);
    if (q == 0) s_node[grp] = node;

    float hs[8];
#pragma unroll
    for (int j = 0; j < 8; ++j) hs[j] = 0.f;

    int e = beg;
    for (; e + 8 <= end; e += 8) {
        int s0 = csr[e + 0], s1 = csr[e + 1], s2 = csr[e + 2], s3 = csr[e + 3];
        int s4 = csr[e + 4], s5 = csr[e + 5], s6 = csr[e + 6], s7 = csr[e + 7];
        int4 a0 = *reinterpret_cast<const int4*>(xbf + (size_t)s0 * DIM + q * 8);
        int4 a1 = *reinterpret_cast<const int4*>(xbf + (size_t)s1 * DIM + q * 8);
        int4 a2 = *reinterpret_cast<const int4*>(xbf + (size_t)s2 * DIM + q * 8);
        int4 a3 = *reinterpret_cast<const int4*>(xbf + (size_t)s3 * DIM + q * 8);
        int4 a4 = *reinterpret_cast<const int4*>(xbf + (size_t)s4 * DIM + q * 8);
        int4 a5 = *reinterpret_cast<const int4*>(xbf + (size_t)s5 * DIM + q * 8);
        int4 a6 = *reinterpret_cast<const int4*>(xbf + (size_t)s6 * DIM + q * 8);
        int4 a7 = *reinterpret_cast<const int4*>(xbf + (size_t)s7 * DIM + q * 8);
#define BFACC(a) \
        hs[0] += bflo(a.x); hs[1] += bfhi(a.x); \
        hs[2] += bflo(a.y); hs[3] += bfhi(a.y); \
        hs[4] += bflo(a.z); hs[5] += bfhi(a.z); \
        hs[6] += bflo(a.w); hs[7] += bfhi(a.w);
        BFACC(a0) BFACC(a1) BFACC(a2) BFACC(a3)
        BFACC(a4) BFACC(a5) BFACC(a6) BFACC(a7)
    }
    for (; e + 4 <= end; e += 4) {
        int s0 = csr[e + 0], s1 = csr[e + 1], s2 = csr[e + 2], s3 = csr[e + 3];
        int4 a0 = *reinterpret_cast<const int4*>(xbf + (size_t)s0 * DIM + q * 8);
        int4 a1 = *reinterpret_cast<const int4*>(xbf + (size_t)s1 * DIM + q * 8);
        int4 a2 = *reinterpret_cast<const int4*>(xbf + (size_t)s2 * DIM + q * 8);
        int4 a3 = *reinterpret_cast<const int4*>(xbf + (size_t)s3 * DIM + q * 8);
        BFACC(a0) BFACC(a1) BFACC(a2) BFACC(a3)
    }
    for (; e < end; ++e) {
        int s = csr[e];
        int4 a = *reinterpret_cast<const int4*>(xbf + (size_t)s * DIM + q * 8);
        BFACC(a)
    }
#undef BFACC

    float xv[8];
    if (valid) {
        int4 a = *reinterpret_cast<const int4*>(xbf + (size_t)node * DIM + q * 8);
        xv[0] = bflo(a.x); xv[1] = bfhi(a.x);
        xv[2] = bflo(a.y); xv[3] = bfhi(a.y);
        xv[4] = bflo(a.z); xv[5] = bfhi(a.z);
        xv[6] = bflo(a.w); xv[7] = bfhi(a.w);
    } else {
#pragma unroll
        for (int j = 0; j < 8; ++j) xv[j] = 0.f;
    }

    *reinterpret_cast<float4*>(&lds_h[grp][q * 8 + 0]) = make_float4(hs[0], hs[1], hs[2], hs[3]);
    *reinterpret_cast<float4*>(&lds_h[grp][q * 8 + 4]) = make_float4(hs[4], hs[5], hs[6], hs[7]);
    *reinterpret_cast<float4*>(&lds_x[grp][q * 8 + 0]) = make_float4(xv[0], xv[1], xv[2], xv[3]);
    *reinterpret_cast<float4*>(&lds_x[grp][q * 8 + 4]) = make_float4(xv[4], xv[5], xv[6], xv[7]);
    __syncthreads();

    int mgrp = threadIdx.x >> 4;
    int mq   = threadIdx.x & 15;
    int d0 = s_d0;
    const float* wl = Wl + (size_t)d0 * DIM * DIM + mq * 4;
    const float* wr = Wr + (size_t)d0 * DIM * DIM + mq * 4;
    float4 accA = *reinterpret_cast<const float4*>(bl + d0 * DIM + mq * 4);
    float4 accB = accA;

#pragma unroll 8
    for (int i = 0; i < DIM; ++i) {
        float4 wlv = *reinterpret_cast<const float4*>(wl + i * DIM);
        float4 wrv = *reinterpret_cast<const float4*>(wr + i * DIM);
        float hA = lds_h[mgrp][i],      xA = lds_x[mgrp][i];
        float hB = lds_h[mgrp + 16][i], xB = lds_x[mgrp + 16][i];
        accA.x += hA * wlv.x + xA * wrv.x;
        accA.y += hA * wlv.y + xA * wrv.y;
        accA.z += hA * wlv.z + xA * wrv.z;
        accA.w += hA * wlv.w + xA * wrv.w;
        accB.x += hB * wlv.x + xB * wrv.x;
        accB.y += hB * wlv.y + xB * wrv.y;
        accB.z += hB * wlv.z + xB * wrv.z;
        accB.w += hB * wlv.w + xB * wrv.w;
    }

    int nodeA = s_node[mgrp];
    int nodeB = s_node[mgrp + 16];
    if (nodeA >= 0)
        *reinterpret_cast<float4*>(outf + (size_t)nodeA * DIM + mq * 4) = accA;
    if (nodeB >= 0)
        *reinterpret_cast<float4*>(outf + (size_t)nodeB * DIM + mq * 4) = accB;
}

// ---------------------------------------------------------------------------
// Fused global_add_pool(relu(emb)) + MLP head; one block per graph.
// ---------------------------------------------------------------------------
__global__ void pool_head_kernel(const float* __restrict__ emb,
                                 const int* __restrict__ batch,
                                 const float* __restrict__ W1,
                                 const float* __restrict__ b1,
                                 const float* __restrict__ W2,
                                 const float* __restrict__ b2,
                                 float* __restrict__ pred) {
    __shared__ float red[4][DIM];
    __shared__ float garr[DIM];
    __shared__ float hid[DIM];
    int gi = blockIdx.x;
    int w = threadIdx.x >> 6;
    int lane = threadIdx.x & 63;

    int lo = 0, hi = N_NODES;
    while (lo < hi) { int mid = (lo + hi) >> 1; if (batch[mid] < gi) lo = mid + 1; else hi = mid; }
    int beg = lo;
    hi = N_NODES;
    while (lo < hi) { int mid = (lo + hi) >> 1; if (batch[mid] < gi + 1) lo = mid + 1; else hi = mid; }
    int end = lo;

    float acc = 0.f;
    for (int n = beg + w; n < end; n += 4)
        acc += fmaxf(emb[(size_t)n * DIM + lane], 0.f);
    red[w][lane] = acc;
    __syncthreads();
    if (w == 0)
        garr[lane] = red[0][lane] + red[1][lane] + red[2][lane] + red[3][lane];
    __syncthreads();

    if (threadIdx.x < DIM) {
        int o = threadIdx.x;
        float a = b1[o];
#pragma unroll 8
        for (int i = 0; i < DIM; ++i) a += garr[i] * W1[i * DIM + o];
        hid[o] = a;
    }
    __syncthreads();
    if (threadIdx.x < ODIM) {
        int o = threadIdx.x;
        float p = b2[o];
#pragma unroll 8
        for (int i = 0; i < DIM; ++i) p += hid[i] * W2[i * ODIM + o];
        pred[(size_t)gi * ODIM + o] = p;
    }
}

extern "C" void kernel_launch(void* const* d_in, const int* in_sizes, int n_in,
                              void* d_out, int out_size, void* d_ws, size_t ws_size,
                              hipStream_t stream) {
    const float* x    = (const float*)d_in[0];
    const int* eidx   = (const int*)d_in[1];
    const int* src    = eidx;
    const int* dst    = eidx + N_EDGES;
    const int* batch  = (const int*)d_in[2];
    const float* Wl1  = (const float*)d_in[4];
    const float* bl1  = (const float*)d_in[5];
    const float* Wr1  = (const float*)d_in[6];
    const float* Wl2  = (const float*)d_in[7];
    const float* bl2  = (const float*)d_in[8];
    const float* Wr2  = (const float*)d_in[9];
    const float* W1   = (const float*)d_in[10];
    const float* b1   = (const float*)d_in[11];
    const float* W2   = (const float*)d_in[12];
    const float* b2   = (const float*)d_in[13];

    float* emb  = (float*)d_out;                          // [N_NODES, 64]
    float* pred = (float*)d_out + (size_t)N_NODES * DIM;  // [N_GRAPHS, 32]

    // Workspace
    int* bcur     = (int*)d_ws;                  // [256]
    int* ebase    = bcur + 256;                  // [256]
    int* gcount   = ebase + 256;                 // [32]
    int* gcur     = gcount + NBKT;               // [32]
    int* deg      = gcur + NBKT;                 // [100000]
    int* rowptr   = deg + N_NODES;               // [100004]
    int* nodelist = rowptr + N_NODES + 4;        // [100992]
    int* csr      = nodelist + LIST_PAD;         // [1200000]
    int* pairs    = csr + N_EDGES;               // [196*8192]
    unsigned char* xq  = (unsigned char*)(pairs + NBUK * CAP);   // [N*64] fp8
    unsigned short* hbf = (unsigned short*)(xq + (size_t)N_NODES * DIM);  // [N*64] bf16

    prep_kernel<<<(PREP_THREADS + 255) / 256, 256, 0, stream>>>(x, xq, bcur, gcount, nodelist);
    pass1_bin_kernel<<<P1_NB, 256, 0, stream>>>(src, dst, bcur, pairs);
    escan_kernel<<<1, 256, 0, stream>>>(bcur, ebase, rowptr);
    pass2_kernel<<<NBUK, 256, 0, stream>>>(pairs, bcur, ebase, deg, rowptr, csr, gcount);
    gscan_kernel<<<1, 64, 0, stream>>>(gcount, gcur);
    bucket_scatter_kernel<<<(N_NODES + 255) / 256, 256, 0, stream>>>(deg, gcur, nodelist);

    // conv1: fp8 gather + matvec + relu -> hbf (bf16)
    conv1_fp8_kernel<<<CONV_BLK, 256, 0, stream>>>(xq, rowptr, csr, nodelist,
                                                   Wl1, bl1, Wr1, hbf);
    // conv2: bf16 gather + matvec -> emb (f32, pre-activation output)
    conv2_bf16_kernel<<<CONV_BLK, 256, 0, stream>>>(hbf, rowptr, csr, nodelist,
                                                    Wl2, bl2, Wr2, emb);
    // fused pool + head
    pool_head_kernel<<<N_GRAPHS, 256, 0, stream>>>(emb, batch, W1, b1, W2, b2, pred);
}

// Round 13
// 232.182 us; speedup vs baseline: 1.9000x; 1.0434x over previous
//
#include <hip/hip_runtime.h>

constexpr int N_NODES  = 100000;
constexpr int N_EDGES  = 1200000;
constexpr int N_GRAPHS = 1000;
constexpr int DIM      = 64;
constexpr int ODIM     = 32;
constexpr int MAXD     = 10;

// coarse binning (two-level CSR build, R11-proven)
constexpr int NPB   = 512;
constexpr int NBUK  = (N_NODES + NPB - 1) / NPB;  // 196
constexpr int CAP   = 8192;
constexpr int EPB   = 4096;
constexpr int P1_NB = (N_EDGES + EPB - 1) / EPB;  // 293

// degree-ordering buckets for conv
constexpr int NBKT     = 32;
constexpr int BPAD     = 32;
constexpr int LIST_PAD = N_NODES + NBKT * (BPAD - 1);  // 100992
constexpr int CONV_BLK = LIST_PAD / BPAD;              // 3156

typedef float v2f __attribute__((ext_vector_type(2)));

// ---------------- bf16 helpers -------------------
__device__ __forceinline__ unsigned short f2bf(float f) {
    unsigned u = __float_as_uint(f);
    u = (u + 0x7fffu + ((u >> 16) & 1u)) >> 16;
    return (unsigned short)u;
}
__device__ __forceinline__ float bflo(int u) {
    return __uint_as_float((unsigned)u << 16);
}
__device__ __forceinline__ float bfhi(int u) {
    return __uint_as_float((unsigned)u & 0xffff0000u);
}

// ---------------------------------------------------------------------------
// prep: fused init (bcur/gcount/nodelist) + x f32 -> fp8 table (HW cvt)
// ---------------------------------------------------------------------------
constexpr int PREP_THREADS = N_NODES * DIM / 8;   // 800000
__global__ void prep_kernel(const float* __restrict__ x,
                            unsigned char* __restrict__ xq,
                            int* __restrict__ bcur, int* __restrict__ gcount,
                            int* __restrict__ nodelist) {
    int i = blockIdx.x * 256 + threadIdx.x;
    if (i < LIST_PAD) nodelist[i] = -1;
    if (i < NBUK) bcur[i] = 0;
    if (i < NBKT) gcount[i] = 0;
    if (i < PREP_THREADS) {
        const float4 v0 = *reinterpret_cast<const float4*>(x + (size_t)i * 8);
        const float4 v1 = *reinterpret_cast<const float4*>(x + (size_t)i * 8 + 4);
        int lo = __builtin_amdgcn_cvt_pk_fp8_f32(v0.x, v0.y, 0, false);
        lo = __builtin_amdgcn_cvt_pk_fp8_f32(v0.z, v0.w, lo, true);
        int hi = __builtin_amdgcn_cvt_pk_fp8_f32(v1.x, v1.y, 0, false);
        hi = __builtin_amdgcn_cvt_pk_fp8_f32(v1.z, v1.w, hi, true);
        uint2 o; o.x = (unsigned)lo; o.y = (unsigned)hi;
        *reinterpret_cast<uint2*>(xq + (size_t)i * 8) = o;
    }
}

// ---------------------------------------------------------------------------
// pass1: block counting-sort of EPB edges into NBUK coarse buckets (R11)
// ---------------------------------------------------------------------------
__global__ __launch_bounds__(256) void pass1_bin_kernel(const int* __restrict__ src,
                                                        const int* __restrict__ dst,
                                                        int* __restrict__ bcur,
                                                        int* __restrict__ pairs) {
    __shared__ int hist[NBUK];
    __shared__ int sexcl[NBUK];
    __shared__ int bbase[NBUK];
    __shared__ int sc[256];
    __shared__ int buf[EPB];
    __shared__ unsigned char bid[EPB];
    int t = threadIdx.x;
    for (int i = t; i < NBUK; i += 256) hist[i] = 0;
    __syncthreads();

    int e0 = blockIdx.x * EPB;
    int cnt = min(EPB, N_EDGES - e0);

    int pk[16], pb[16], pr[16];
#pragma unroll
    for (int k = 0; k < 16; ++k) {
        int j = t + k * 256;
        pb[k] = -1;
        if (j < cnt) {
            int s = src[e0 + j];
            int d = dst[e0 + j];
            int b = d >> 9;
            pb[k] = b;
            pk[k] = s | ((d & (NPB - 1)) << 17);
            pr[k] = atomicAdd(&hist[b], 1);
        }
    }
    __syncthreads();

    int v = (t < NBUK) ? hist[t] : 0;
    sc[t] = v;
    __syncthreads();
    for (int off = 1; off < 256; off <<= 1) {
        int u = (t >= off) ? sc[t - off] : 0;
        __syncthreads();
        sc[t] += u;
        __syncthreads();
    }
    if (t < NBUK) {
        sexcl[t] = sc[t] - v;
        bbase[t] = v ? atomicAdd(&bcur[t], v) : 0;
    }
    __syncthreads();

#pragma unroll
    for (int k = 0; k < 16; ++k) {
        if (pb[k] >= 0) {
            int pos = sexcl[pb[k]] + pr[k];
            buf[pos] = pk[k];
            bid[pos] = (unsigned char)pb[k];
        }
    }
    __syncthreads();

#pragma unroll
    for (int k = 0; k < 16; ++k) {
        int j = t + k * 256;
        if (j < cnt) {
            int b = bid[j];
            pairs[(size_t)b * CAP + bbase[b] + (j - sexcl[b])] = buf[j];
        }
    }
}

// ---------------------------------------------------------------------------
// escan: exclusive scan of bucket counts -> ebase; rowptr[N]=E
// ---------------------------------------------------------------------------
__global__ void escan_kernel(const int* __restrict__ bcur, int* __restrict__ ebase,
                             int* __restrict__ rowptr) {
    __shared__ int sc[256];
    int t = threadIdx.x;
    int v = (t < NBUK) ? bcur[t] : 0;
    sc[t] = v;
    __syncthreads();
    for (int off = 1; off < 256; off <<= 1) {
        int u = (t >= off) ? sc[t - off] : 0;
        __syncthreads();
        sc[t] += u;
        __syncthreads();
    }
    if (t < NBUK) ebase[t] = sc[t] - v;
    if (t == NBUK - 1) ebase[NBUK] = sc[t];
    if (t == 0) rowptr[N_NODES] = N_EDGES;
}

// ---------------------------------------------------------------------------
// pass2: one block per coarse bucket: deg/rowptr writeout + csr scatter (R11)
// ---------------------------------------------------------------------------
__global__ __launch_bounds__(256) void pass2_kernel(const int* __restrict__ pairs,
                                                    const int* __restrict__ bcnt,
                                                    const int* __restrict__ ebase,
                                                    int* __restrict__ deg,
                                                    int* __restrict__ rowptr,
                                                    int* __restrict__ csr,
                                                    int* __restrict__ gcount) {
    __shared__ int dh[NPB];
    __shared__ int sc[256];
    __shared__ int gh[NBKT];
    int b = blockIdx.x, t = threadIdx.x;
    int nbeg = b * NPB;
    int nn = min(NPB, N_NODES - nbeg);
    int cnt = bcnt[b];
    int base = ebase[b];
    const int* reg = pairs + (size_t)b * CAP;

    for (int i = t; i < NPB; i += 256) dh[i] = 0;
    if (t < NBKT) gh[t] = 0;
    __syncthreads();

    for (int j = t; j < cnt; j += 256)
        atomicAdd(&dh[reg[j] >> 17], 1);
    __syncthreads();

    int a0 = dh[2 * t];
    int a1 = dh[2 * t + 1];
    sc[t] = a0 + a1;
    __syncthreads();
    for (int off = 1; off < 256; off <<= 1) {
        int u = (t >= off) ? sc[t - off] : 0;
        __syncthreads();
        sc[t] += u;
        __syncthreads();
    }
    int e0 = sc[t] - (a0 + a1);
    int e1 = e0 + a0;
    int i0 = 2 * t, i1 = 2 * t + 1;
    if (i0 < nn) {
        deg[nbeg + i0] = a0;
        rowptr[nbeg + i0] = base + e0;
        atomicAdd(&gh[min(a0, NBKT - 1)], 1);
    }
    if (i1 < nn) {
        deg[nbeg + i1] = a1;
        rowptr[nbeg + i1] = base + e1;
        atomicAdd(&gh[min(a1, NBKT - 1)], 1);
    }
    __syncthreads();
    dh[i0] = e0;
    dh[i1] = e1;
    __syncthreads();

    for (int j = t; j < cnt; j += 256) {
        int p = reg[j];
        int r = atomicAdd(&dh[p >> 17], 1);
        csr[base + r] = p & 0x1FFFF;
    }
    __syncthreads();
    if (t < NBKT && gh[t]) atomicAdd(&gcount[t], gh[t]);
}

// ---------------------------------------------------------------------------
// gscan + bucket scatter (R11)
// ---------------------------------------------------------------------------
__global__ void gscan_kernel(const int* __restrict__ gcount, int* __restrict__ gcur) {
    if (threadIdx.x == 0) {
        int off = 0;
        for (int k = 0; k < NBKT; ++k) {
            gcur[k] = off;
            off += (gcount[k] + BPAD - 1) & ~(BPAD - 1);
        }
    }
}

__global__ void bucket_scatter_kernel(const int* __restrict__ deg,
                                      int* __restrict__ gcur,
                                      int* __restrict__ nodelist) {
    __shared__ int lh[NBKT], lbase[NBKT];
    int t = threadIdx.x;
    if (t < NBKT) lh[t] = 0;
    __syncthreads();
    int i = blockIdx.x * 256 + t;
    int k = 0, r = 0;
    bool valid = (i < N_NODES);
    if (valid) {
        k = min(deg[i], NBKT - 1);
        r = atomicAdd(&lh[k], 1);
    }
    __syncthreads();
    if (t < NBKT && lh[t]) lbase[t] = atomicAdd(&gcur[t], lh[t]);
    __syncthreads();
    if (valid) nodelist[lbase[k] + r] = i;
}

// ---------------------------------------------------------------------------
// conv1: fp8 gather (64B rows, HW cvt decode) + matvec + relu -> bf16 out
// ---------------------------------------------------------------------------
__global__ __launch_bounds__(256) void conv1_fp8_kernel(
        const unsigned char* __restrict__ xq,
        const int* __restrict__ rowptr,
        const int* __restrict__ csr,
        const int* __restrict__ nodelist,
        const float* __restrict__ Wl,
        const float* __restrict__ bl,
        const float* __restrict__ Wr,
        unsigned short* __restrict__ outb) {
    __shared__ float lds_h[BPAD][DIM + 4];
    __shared__ float lds_x[BPAD][DIM + 4];
    __shared__ int s_node[BPAD];
    __shared__ int s_d0;

    int base = blockIdx.x * BPAD;
    int node0 = nodelist[base];
    if (node0 < 0) return;

    int grp = threadIdx.x >> 3;
    int q   = threadIdx.x & 7;
    int node = nodelist[base + grp];
    bool valid = (node >= 0);

    int beg = 0, end = 0;
    if (valid) { beg = rowptr[node]; end = rowptr[node + 1]; }

    if (threadIdx.x == 0) s_d0 = min(end - beg, MAXD);
    if (q == 0) s_node[grp] = node;

    float hs[8];
#pragma unroll
    for (int j = 0; j < 8; ++j) hs[j] = 0.f;

#define QACC(a) { \
    v2f p0 = __builtin_amdgcn_cvt_pk_f32_fp8((a).x, false); \
    v2f p1 = __builtin_amdgcn_cvt_pk_f32_fp8((a).x, true); \
    v2f p2 = __builtin_amdgcn_cvt_pk_f32_fp8((a).y, false); \
    v2f p3 = __builtin_amdgcn_cvt_pk_f32_fp8((a).y, true); \
    hs[0] += p0.x; hs[1] += p0.y; hs[2] += p1.x; hs[3] += p1.y; \
    hs[4] += p2.x; hs[5] += p2.y; hs[6] += p3.x; hs[7] += p3.y; }

    int e = beg;
    for (; e + 8 <= end; e += 8) {
        int s0 = csr[e + 0], s1 = csr[e + 1], s2 = csr[e + 2], s3 = csr[e + 3];
        int s4 = csr[e + 4], s5 = csr[e + 5], s6 = csr[e + 6], s7 = csr[e + 7];
        uint2 a0 = *reinterpret_cast<const uint2*>(xq + (size_t)s0 * DIM + q * 8);
        uint2 a1 = *reinterpret_cast<const uint2*>(xq + (size_t)s1 * DIM + q * 8);
        uint2 a2 = *reinterpret_cast<const uint2*>(xq + (size_t)s2 * DIM + q * 8);
        uint2 a3 = *reinterpret_cast<const uint2*>(xq + (size_t)s3 * DIM + q * 8);
        uint2 a4 = *reinterpret_cast<const uint2*>(xq + (size_t)s4 * DIM + q * 8);
        uint2 a5 = *reinterpret_cast<const uint2*>(xq + (size_t)s5 * DIM + q * 8);
        uint2 a6 = *reinterpret_cast<const uint2*>(xq + (size_t)s6 * DIM + q * 8);
        uint2 a7 = *reinterpret_cast<const uint2*>(xq + (size_t)s7 * DIM + q * 8);
        QACC(a0) QACC(a1) QACC(a2) QACC(a3)
        QACC(a4) QACC(a5) QACC(a6) QACC(a7)
    }
    for (; e + 4 <= end; e += 4) {
        int s0 = csr[e + 0], s1 = csr[e + 1], s2 = csr[e + 2], s3 = csr[e + 3];
        uint2 a0 = *reinterpret_cast<const uint2*>(xq + (size_t)s0 * DIM + q * 8);
        uint2 a1 = *reinterpret_cast<const uint2*>(xq + (size_t)s1 * DIM + q * 8);
        uint2 a2 = *reinterpret_cast<const uint2*>(xq + (size_t)s2 * DIM + q * 8);
        uint2 a3 = *reinterpret_cast<const uint2*>(xq + (size_t)s3 * DIM + q * 8);
        QACC(a0) QACC(a1) QACC(a2) QACC(a3)
    }
    for (; e < end; ++e) {
        int s = csr[e];
        uint2 a = *reinterpret_cast<const uint2*>(xq + (size_t)s * DIM + q * 8);
        QACC(a)
    }
#undef QACC

    float xv[8];
    if (valid) {
        uint2 a = *reinterpret_cast<const uint2*>(xq + (size_t)node * DIM + q * 8);
        v2f p0 = __builtin_amdgcn_cvt_pk_f32_fp8(a.x, false);
        v2f p1 = __builtin_amdgcn_cvt_pk_f32_fp8(a.x, true);
        v2f p2 = __builtin_amdgcn_cvt_pk_f32_fp8(a.y, false);
        v2f p3 = __builtin_amdgcn_cvt_pk_f32_fp8(a.y, true);
        xv[0] = p0.x; xv[1] = p0.y; xv[2] = p1.x; xv[3] = p1.y;
        xv[4] = p2.x; xv[5] = p2.y; xv[6] = p3.x; xv[7] = p3.y;
    } else {
#pragma unroll
        for (int j = 0; j < 8; ++j) xv[j] = 0.f;
    }

    *reinterpret_cast<float4*>(&lds_h[grp][q * 8 + 0]) = make_float4(hs[0], hs[1], hs[2], hs[3]);
    *reinterpret_cast<float4*>(&lds_h[grp][q * 8 + 4]) = make_float4(hs[4], hs[5], hs[6], hs[7]);
    *reinterpret_cast<float4*>(&lds_x[grp][q * 8 + 0]) = make_float4(xv[0], xv[1], xv[2], xv[3]);
    *reinterpret_cast<float4*>(&lds_x[grp][q * 8 + 4]) = make_float4(xv[4], xv[5], xv[6], xv[7]);
    __syncthreads();

    int mgrp = threadIdx.x >> 4;
    int mq   = threadIdx.x & 15;
    int d0 = s_d0;
    const float* wl = Wl + (size_t)d0 * DIM * DIM + mq * 4;
    const float* wr = Wr + (size_t)d0 * DIM * DIM + mq * 4;
    float4 accA = *reinterpret_cast<const float4*>(bl + d0 * DIM + mq * 4);
    float4 accB = accA;

#pragma unroll 8
    for (int i = 0; i < DIM; ++i) {
        float4 wlv = *reinterpret_cast<const float4*>(wl + i * DIM);
        float4 wrv = *reinterpret_cast<const float4*>(wr + i * DIM);
        float hA = lds_h[mgrp][i],      xA = lds_x[mgrp][i];
        float hB = lds_h[mgrp + 16][i], xB = lds_x[mgrp + 16][i];
        accA.x += hA * wlv.x + xA * wrv.x;
        accA.y += hA * wlv.y + xA * wrv.y;
        accA.z += hA * wlv.z + xA * wrv.z;
        accA.w += hA * wlv.w + xA * wrv.w;
        accB.x += hB * wlv.x + xB * wrv.x;
        accB.y += hB * wlv.y + xB * wrv.y;
        accB.z += hB * wlv.z + xB * wrv.z;
        accB.w += hB * wlv.w + xB * wrv.w;
    }

    int nodeA = s_node[mgrp];
    int nodeB = s_node[mgrp + 16];
    if (nodeA >= 0) {
        ushort4 o;
        o.x = f2bf(fmaxf(accA.x, 0.f)); o.y = f2bf(fmaxf(accA.y, 0.f));
        o.z = f2bf(fmaxf(accA.z, 0.f)); o.w = f2bf(fmaxf(accA.w, 0.f));
        *reinterpret_cast<ushort4*>(outb + (size_t)nodeA * DIM + mq * 4) = o;
    }
    if (nodeB >= 0) {
        ushort4 o;
        o.x = f2bf(fmaxf(accB.x, 0.f)); o.y = f2bf(fmaxf(accB.y, 0.f));
        o.z = f2bf(fmaxf(accB.z, 0.f)); o.w = f2bf(fmaxf(accB.w, 0.f));
        *reinterpret_cast<ushort4*>(outb + (size_t)nodeB * DIM + mq * 4) = o;
    }
}

// ---------------------------------------------------------------------------
// conv2: bf16 gather + matvec -> f32 emb (R11-proven)
// ---------------------------------------------------------------------------
__global__ __launch_bounds__(256) void conv2_bf16_kernel(
        const unsigned short* __restrict__ xbf,
        const int* __restrict__ rowptr,
        const int* __restrict__ csr,
        const int* __restrict__ nodelist,
        const float* __restrict__ Wl,
        const float* __restrict__ bl,
        const float* __restrict__ Wr,
        float* __restrict__ outf) {
    __shared__ float lds_h[BPAD][DIM + 4];
    __shared__ float lds_x[BPAD][DIM + 4];
    __shared__ int s_node[BPAD];
    __shared__ int s_d0;

    int base = blockIdx.x * BPAD;
    int node0 = nodelist[base];
    if (node0 < 0) return;

    int grp = threadIdx.x >> 3;
    int q   = threadIdx.x & 7;
    int node = nodelist[base + grp];
    bool valid = (node >= 0);

    int beg = 0, end = 0;
    if (valid) { beg = rowptr[node]; end = rowptr[node + 1]; }

    if (threadIdx.x == 0) s_d0 = min(end - beg, MAXD);
    if (q == 0) s_node[grp] = node;

    float hs[8];
#pragma unroll
    for (int j = 0; j < 8; ++j) hs[j] = 0.f;

    int e = beg;
    for (; e + 8 <= end; e += 8) {
        int s0 = csr[e + 0], s1 = csr[e + 1], s2 = csr[e + 2], s3 = csr[e + 3];
        int s4 = csr[e + 4], s5 = csr[e + 5], s6 = csr[e + 6], s7 = csr[e + 7];
        int4 a0 = *reinterpret_cast<const int4*>(xbf + (size_t)s0 * DIM + q * 8);
        int4 a1 = *reinterpret_cast<const int4*>(xbf + (size_t)s1 * DIM + q * 8);
        int4 a2 = *reinterpret_cast<const int4*>(xbf + (size_t)s2 * DIM + q * 8);
        int4 a3 = *reinterpret_cast<const int4*>(xbf + (size_t)s3 * DIM + q * 8);
        int4 a4 = *reinterpret_cast<const int4*>(xbf + (size_t)s4 * DIM + q * 8);
        int4 a5 = *reinterpret_cast<const int4*>(xbf + (size_t)s5 * DIM + q * 8);
        int4 a6 = *reinterpret_cast<const int4*>(xbf + (size_t)s6 * DIM + q * 8);
        int4 a7 = *reinterpret_cast<const int4*>(xbf + (size_t)s7 * DIM + q * 8);
#define BFACC(a) \
        hs[0] += bflo(a.x); hs[1] += bfhi(a.x); \
        hs[2] += bflo(a.y); hs[3] += bfhi(a.y); \
        hs[4] += bflo(a.z); hs[5] += bfhi(a.z); \
        hs[6] += bflo(a.w); hs[7] += bfhi(a.w);
        BFACC(a0) BFACC(a1) BFACC(a2) BFACC(a3)
        BFACC(a4) BFACC(a5) BFACC(a6) BFACC(a7)
    }
    for (; e + 4 <= end; e += 4) {
        int s0 = csr[e + 0], s1 = csr[e + 1], s2 = csr[e + 2], s3 = csr[e + 3];
        int4 a0 = *reinterpret_cast<const int4*>(xbf + (size_t)s0 * DIM + q * 8);
        int4 a1 = *reinterpret_cast<const int4*>(xbf + (size_t)s1 * DIM + q * 8);
        int4 a2 = *reinterpret_cast<const int4*>(xbf + (size_t)s2 * DIM + q * 8);
        int4 a3 = *reinterpret_cast<const int4*>(xbf + (size_t)s3 * DIM + q * 8);
        BFACC(a0) BFACC(a1) BFACC(a2) BFACC(a3)
    }
    for (; e < end; ++e) {
        int s = csr[e];
        int4 a = *reinterpret_cast<const int4*>(xbf + (size_t)s * DIM + q * 8);
        BFACC(a)
    }
#undef BFACC

    float xv[8];
    if (valid) {
        int4 a = *reinterpret_cast<const int4*>(xbf + (size_t)node * DIM + q * 8);
        xv[0] = bflo(a.x); xv[1] = bfhi(a.x);
        xv[2] = bflo(a.y); xv[3] = bfhi(a.y);
        xv[4] = bflo(a.z); xv[5] = bfhi(a.z);
        xv[6] = bflo(a.w); xv[7] = bfhi(a.w);
    } else {
#pragma unroll
        for (int j = 0; j < 8; ++j) xv[j] = 0.f;
    }

    *reinterpret_cast<float4*>(&lds_h[grp][q * 8 + 0]) = make_float4(hs[0], hs[1], hs[2], hs[3]);
    *reinterpret_cast<float4*>(&lds_h[grp][q * 8 + 4]) = make_float4(hs[4], hs[5], hs[6], hs[7]);
    *reinterpret_cast<float4*>(&lds_x[grp][q * 8 + 0]) = make_float4(xv[0], xv[1], xv[2], xv[3]);
    *reinterpret_cast<float4*>(&lds_x[grp][q * 8 + 4]) = make_float4(xv[4], xv[5], xv[6], xv[7]);
    __syncthreads();

    int mgrp = threadIdx.x >> 4;
    int mq   = threadIdx.x & 15;
    int d0 = s_d0;
    const float* wl = Wl + (size_t)d0 * DIM * DIM + mq * 4;
    const float* wr = Wr + (size_t)d0 * DIM * DIM + mq * 4;
    float4 accA = *reinterpret_cast<const float4*>(bl + d0 * DIM + mq * 4);
    float4 accB = accA;

#pragma unroll 8
    for (int i = 0; i < DIM; ++i) {
        float4 wlv = *reinterpret_cast<const float4*>(wl + i * DIM);
        float4 wrv = *reinterpret_cast<const float4*>(wr + i * DIM);
        float hA = lds_h[mgrp][i],      xA = lds_x[mgrp][i];
        float hB = lds_h[mgrp + 16][i], xB = lds_x[mgrp + 16][i];
        accA.x += hA * wlv.x + xA * wrv.x;
        accA.y += hA * wlv.y + xA * wrv.y;
        accA.z += hA * wlv.z + xA * wrv.z;
        accA.w += hA * wlv.w + xA * wrv.w;
        accB.x += hB * wlv.x + xB * wrv.x;
        accB.y += hB * wlv.y + xB * wrv.y;
        accB.z += hB * wlv.z + xB * wrv.z;
        accB.w += hB * wlv.w + xB * wrv.w;
    }

    int nodeA = s_node[mgrp];
    int nodeB = s_node[mgrp + 16];
    if (nodeA >= 0)
        *reinterpret_cast<float4*>(outf + (size_t)nodeA * DIM + mq * 4) = accA;
    if (nodeB >= 0)
        *reinterpret_cast<float4*>(outf + (size_t)nodeB * DIM + mq * 4) = accB;
}

// ---------------------------------------------------------------------------
// Fused global_add_pool(relu(emb)) + MLP head; one block per graph.
// ---------------------------------------------------------------------------
__global__ void pool_head_kernel(const float* __restrict__ emb,
                                 const int* __restrict__ batch,
                                 const float* __restrict__ W1,
                                 const float* __restrict__ b1,
                                 const float* __restrict__ W2,
                                 const float* __restrict__ b2,
                                 float* __restrict__ pred) {
    __shared__ float red[4][DIM];
    __shared__ float garr[DIM];
    __shared__ float hid[DIM];
    int gi = blockIdx.x;
    int w = threadIdx.x >> 6;
    int lane = threadIdx.x & 63;

    int lo = 0, hi = N_NODES;
    while (lo < hi) { int mid = (lo + hi) >> 1; if (batch[mid] < gi) lo = mid + 1; else hi = mid; }
    int beg = lo;
    hi = N_NODES;
    while (lo < hi) { int mid = (lo + hi) >> 1; if (batch[mid] < gi + 1) lo = mid + 1; else hi = mid; }
    int end = lo;

    float acc = 0.f;
    for (int n = beg + w; n < end; n += 4)
        acc += fmaxf(emb[(size_t)n * DIM + lane], 0.f);
    red[w][lane] = acc;
    __syncthreads();
    if (w == 0)
        garr[lane] = red[0][lane] + red[1][lane] + red[2][lane] + red[3][lane];
    __syncthreads();

    if (threadIdx.x < DIM) {
        int o = threadIdx.x;
        float a = b1[o];
#pragma unroll 8
        for (int i = 0; i < DIM; ++i) a += garr[i] * W1[i * DIM + o];
        hid[o] = a;
    }
    __syncthreads();
    if (threadIdx.x < ODIM) {
        int o = threadIdx.x;
        float p = b2[o];
#pragma unroll 8
        for (int i = 0; i < DIM; ++i) p += hid[i] * W2[i * ODIM + o];
        pred[(size_t)gi * ODIM + o] = p;
    }
}

extern "C" void kernel_launch(void* const* d_in, const int* in_sizes, int n_in,
                              void* d_out, int out_size, void* d_ws, size_t ws_size,
                              hipStream_t stream) {
    const float* x    = (const float*)d_in[0];
    const int* eidx   = (const int*)d_in[1];
    const int* src    = eidx;
    const int* dst    = eidx + N_EDGES;
    const int* batch  = (const int*)d_in[2];
    const float* Wl1  = (const float*)d_in[4];
    const float* bl1  = (const float*)d_in[5];
    const float* Wr1  = (const float*)d_in[6];
    const float* Wl2  = (const float*)d_in[7];
    const float* bl2  = (const float*)d_in[8];
    const float* Wr2  = (const float*)d_in[9];
    const float* W1   = (const float*)d_in[10];
    const float* b1   = (const float*)d_in[11];
    const float* W2   = (const float*)d_in[12];
    const float* b2   = (const float*)d_in[13];

    float* emb  = (float*)d_out;                          // [N_NODES, 64]
    float* pred = (float*)d_out + (size_t)N_NODES * DIM;  // [N_GRAPHS, 32]

    // Workspace
    int* bcur     = (int*)d_ws;                  // [256]
    int* ebase    = bcur + 256;                  // [256]
    int* gcount   = ebase + 256;                 // [32]
    int* gcur     = gcount + NBKT;               // [32]
    int* deg      = gcur + NBKT;                 // [100000]
    int* rowptr   = deg + N_NODES;               // [100004]
    int* nodelist = rowptr + N_NODES + 4;        // [100992]
    int* csr      = nodelist + LIST_PAD;         // [1200000]
    int* pairs    = csr + N_EDGES;               // [196*8192]
    unsigned char* xq  = (unsigned char*)(pairs + NBUK * CAP);   // [N*64] fp8
    unsigned short* hbf = (unsigned short*)(xq + (size_t)N_NODES * DIM);  // [N*64] bf16

    prep_kernel<<<(PREP_THREADS + 255) / 256, 256, 0, stream>>>(x, xq, bcur, gcount, nodelist);
    pass1_bin_kernel<<<P1_NB, 256, 0, stream>>>(src, dst, bcur, pairs);
    escan_kernel<<<1, 256, 0, stream>>>(bcur, ebase, rowptr);
    pass2_kernel<<<NBUK, 256, 0, stream>>>(pairs, bcur, ebase, deg, rowptr, csr, gcount);
    gscan_kernel<<<1, 64, 0, stream>>>(gcount, gcur);
    bucket_scatter_kernel<<<(N_NODES + 255) / 256, 256, 0, stream>>>(deg, gcur, nodelist);

    // conv1: fp8 gather (HW cvt) + matvec + relu -> hbf (bf16)
    conv1_fp8_kernel<<<CONV_BLK, 256, 0, stream>>>(xq, rowptr, csr, nodelist,
                                                   Wl1, bl1, Wr1, hbf);
    // conv2: bf16 gather + matvec -> emb (f32, pre-activation output)
    conv2_bf16_kernel<<<CONV_BLK, 256, 0, stream>>>(hbf, rowptr, csr, nodelist,
                                                    Wl2, bl2, Wr2, emb);
    // fused pool + head
    pool_head_kernel<<<N_GRAPHS, 256, 0, stream>>>(emb, batch, W1, b1, W2, b2, pred);
}

// Round 14
// 220.890 us; speedup vs baseline: 1.9971x; 1.0511x over previous
//
#include <hip/hip_runtime.h>

constexpr int N_NODES  = 100000;
constexpr int N_EDGES  = 1200000;
constexpr int N_GRAPHS = 1000;
constexpr int DIM      = 64;
constexpr int ODIM     = 32;
constexpr int MAXD     = 10;

// coarse binning (two-level CSR build, R11-proven)
constexpr int NPB   = 512;
constexpr int NBUK  = (N_NODES + NPB - 1) / NPB;  // 196
constexpr int CAP   = 8192;
constexpr int EPB   = 4096;
constexpr int P1_NB = (N_EDGES + EPB - 1) / EPB;  // 293

// degree-ordering buckets for conv
constexpr int NBKT     = 32;
constexpr int BPAD     = 32;
constexpr int LIST_PAD = N_NODES + NBKT * (BPAD - 1);  // 100992
constexpr int CONV_BLK = LIST_PAD / BPAD;              // 3156

typedef float v2f __attribute__((ext_vector_type(2)));

// ---------------- bf16 helpers -------------------
__device__ __forceinline__ unsigned short f2bf(float f) {
    unsigned u = __float_as_uint(f);
    u = (u + 0x7fffu + ((u >> 16) & 1u)) >> 16;
    return (unsigned short)u;
}

// ---------------------------------------------------------------------------
// prep: fused init (bcur/gcount/nodelist) + x f32 -> fp8 table (HW cvt)
// ---------------------------------------------------------------------------
constexpr int PREP_THREADS = N_NODES * DIM / 8;   // 800000
__global__ void prep_kernel(const float* __restrict__ x,
                            unsigned char* __restrict__ xq,
                            int* __restrict__ bcur, int* __restrict__ gcount,
                            int* __restrict__ nodelist) {
    int i = blockIdx.x * 256 + threadIdx.x;
    if (i < LIST_PAD) nodelist[i] = -1;
    if (i < NBUK) bcur[i] = 0;
    if (i < NBKT) gcount[i] = 0;
    if (i < PREP_THREADS) {
        const float4 v0 = *reinterpret_cast<const float4*>(x + (size_t)i * 8);
        const float4 v1 = *reinterpret_cast<const float4*>(x + (size_t)i * 8 + 4);
        int lo = __builtin_amdgcn_cvt_pk_fp8_f32(v0.x, v0.y, 0, false);
        lo = __builtin_amdgcn_cvt_pk_fp8_f32(v0.z, v0.w, lo, true);
        int hi = __builtin_amdgcn_cvt_pk_fp8_f32(v1.x, v1.y, 0, false);
        hi = __builtin_amdgcn_cvt_pk_fp8_f32(v1.z, v1.w, hi, true);
        uint2 o; o.x = (unsigned)lo; o.y = (unsigned)hi;
        *reinterpret_cast<uint2*>(xq + (size_t)i * 8) = o;
    }
}

// ---------------------------------------------------------------------------
// pass1: block counting-sort of EPB edges into NBUK coarse buckets (R11)
// ---------------------------------------------------------------------------
__global__ __launch_bounds__(256) void pass1_bin_kernel(const int* __restrict__ src,
                                                        const int* __restrict__ dst,
                                                        int* __restrict__ bcur,
                                                        int* __restrict__ pairs) {
    __shared__ int hist[NBUK];
    __shared__ int sexcl[NBUK];
    __shared__ int bbase[NBUK];
    __shared__ int sc[256];
    __shared__ int buf[EPB];
    __shared__ unsigned char bid[EPB];
    int t = threadIdx.x;
    for (int i = t; i < NBUK; i += 256) hist[i] = 0;
    __syncthreads();

    int e0 = blockIdx.x * EPB;
    int cnt = min(EPB, N_EDGES - e0);

    int pk[16], pb[16], pr[16];
#pragma unroll
    for (int k = 0; k < 16; ++k) {
        int j = t + k * 256;
        pb[k] = -1;
        if (j < cnt) {
            int s = src[e0 + j];
            int d = dst[e0 + j];
            int b = d >> 9;
            pb[k] = b;
            pk[k] = s | ((d & (NPB - 1)) << 17);
            pr[k] = atomicAdd(&hist[b], 1);
        }
    }
    __syncthreads();

    int v = (t < NBUK) ? hist[t] : 0;
    sc[t] = v;
    __syncthreads();
    for (int off = 1; off < 256; off <<= 1) {
        int u = (t >= off) ? sc[t - off] : 0;
        __syncthreads();
        sc[t] += u;
        __syncthreads();
    }
    if (t < NBUK) {
        sexcl[t] = sc[t] - v;
        bbase[t] = v ? atomicAdd(&bcur[t], v) : 0;
    }
    __syncthreads();

#pragma unroll
    for (int k = 0; k < 16; ++k) {
        if (pb[k] >= 0) {
            int pos = sexcl[pb[k]] + pr[k];
            buf[pos] = pk[k];
            bid[pos] = (unsigned char)pb[k];
        }
    }
    __syncthreads();

#pragma unroll
    for (int k = 0; k < 16; ++k) {
        int j = t + k * 256;
        if (j < cnt) {
            int b = bid[j];
            pairs[(size_t)b * CAP + bbase[b] + (j - sexcl[b])] = buf[j];
        }
    }
}

// ---------------------------------------------------------------------------
// escan: exclusive scan of bucket counts -> ebase; rowptr[N]=E
// ---------------------------------------------------------------------------
__global__ void escan_kernel(const int* __restrict__ bcur, int* __restrict__ ebase,
                             int* __restrict__ rowptr) {
    __shared__ int sc[256];
    int t = threadIdx.x;
    int v = (t < NBUK) ? bcur[t] : 0;
    sc[t] = v;
    __syncthreads();
    for (int off = 1; off < 256; off <<= 1) {
        int u = (t >= off) ? sc[t - off] : 0;
        __syncthreads();
        sc[t] += u;
        __syncthreads();
    }
    if (t < NBUK) ebase[t] = sc[t] - v;
    if (t == NBUK - 1) ebase[NBUK] = sc[t];
    if (t == 0) rowptr[N_NODES] = N_EDGES;
}

// ---------------------------------------------------------------------------
// pass2: one block per coarse bucket: deg/rowptr writeout + csr scatter (R11)
// ---------------------------------------------------------------------------
__global__ __launch_bounds__(256) void pass2_kernel(const int* __restrict__ pairs,
                                                    const int* __restrict__ bcnt,
                                                    const int* __restrict__ ebase,
                                                    int* __restrict__ deg,
                                                    int* __restrict__ rowptr,
                                                    int* __restrict__ csr,
                                                    int* __restrict__ gcount) {
    __shared__ int dh[NPB];
    __shared__ int sc[256];
    __shared__ int gh[NBKT];
    int b = blockIdx.x, t = threadIdx.x;
    int nbeg = b * NPB;
    int nn = min(NPB, N_NODES - nbeg);
    int cnt = bcnt[b];
    int base = ebase[b];
    const int* reg = pairs + (size_t)b * CAP;

    for (int i = t; i < NPB; i += 256) dh[i] = 0;
    if (t < NBKT) gh[t] = 0;
    __syncthreads();

    for (int j = t; j < cnt; j += 256)
        atomicAdd(&dh[reg[j] >> 17], 1);
    __syncthreads();

    int a0 = dh[2 * t];
    int a1 = dh[2 * t + 1];
    sc[t] = a0 + a1;
    __syncthreads();
    for (int off = 1; off < 256; off <<= 1) {
        int u = (t >= off) ? sc[t - off] : 0;
        __syncthreads();
        sc[t] += u;
        __syncthreads();
    }
    int e0 = sc[t] - (a0 + a1);
    int e1 = e0 + a0;
    int i0 = 2 * t, i1 = 2 * t + 1;
    if (i0 < nn) {
        deg[nbeg + i0] = a0;
        rowptr[nbeg + i0] = base + e0;
        atomicAdd(&gh[min(a0, NBKT - 1)], 1);
    }
    if (i1 < nn) {
        deg[nbeg + i1] = a1;
        rowptr[nbeg + i1] = base + e1;
        atomicAdd(&gh[min(a1, NBKT - 1)], 1);
    }
    __syncthreads();
    dh[i0] = e0;
    dh[i1] = e1;
    __syncthreads();

    for (int j = t; j < cnt; j += 256) {
        int p = reg[j];
        int r = atomicAdd(&dh[p >> 17], 1);
        csr[base + r] = p & 0x1FFFF;
    }
    __syncthreads();
    if (t < NBKT && gh[t]) atomicAdd(&gcount[t], gh[t]);
}

// ---------------------------------------------------------------------------
// gscan + bucket scatter (R11)
// ---------------------------------------------------------------------------
__global__ void gscan_kernel(const int* __restrict__ gcount, int* __restrict__ gcur) {
    if (threadIdx.x == 0) {
        int off = 0;
        for (int k = 0; k < NBKT; ++k) {
            gcur[k] = off;
            off += (gcount[k] + BPAD - 1) & ~(BPAD - 1);
        }
    }
}

__global__ void bucket_scatter_kernel(const int* __restrict__ deg,
                                      int* __restrict__ gcur,
                                      int* __restrict__ nodelist) {
    __shared__ int lh[NBKT], lbase[NBKT];
    int t = threadIdx.x;
    if (t < NBKT) lh[t] = 0;
    __syncthreads();
    int i = blockIdx.x * 256 + t;
    int k = 0, r = 0;
    bool valid = (i < N_NODES);
    if (valid) {
        k = min(deg[i], NBKT - 1);
        r = atomicAdd(&lh[k], 1);
    }
    __syncthreads();
    if (t < NBKT && lh[t]) lbase[t] = atomicAdd(&gcur[t], lh[t]);
    __syncthreads();
    if (valid) nodelist[lbase[k] + r] = i;
}

// ---------------------------------------------------------------------------
// Shared conv body: fp8 gather (64B rows, HW cvt) + bucketed matvec.
// OUTMODE 0: write f32 rows to outf (emb).
// OUTMODE 1: relu + HW fp8 encode -> outq (table for conv2).
// ---------------------------------------------------------------------------
template <int OUTMODE>
__global__ __launch_bounds__(256) void conv_fp8_kernel(
        const unsigned char* __restrict__ xq,
        const int* __restrict__ rowptr,
        const int* __restrict__ csr,
        const int* __restrict__ nodelist,
        const float* __restrict__ Wl,
        const float* __restrict__ bl,
        const float* __restrict__ Wr,
        float* __restrict__ outf,
        unsigned char* __restrict__ outq) {
    __shared__ float lds_h[BPAD][DIM + 4];
    __shared__ float lds_x[BPAD][DIM + 4];
    __shared__ int s_node[BPAD];
    __shared__ int s_d0;

    int base = blockIdx.x * BPAD;
    int node0 = nodelist[base];
    if (node0 < 0) return;

    int grp = threadIdx.x >> 3;
    int q   = threadIdx.x & 7;
    int node = nodelist[base + grp];
    bool valid = (node >= 0);

    int beg = 0, end = 0;
    if (valid) { beg = rowptr[node]; end = rowptr[node + 1]; }

    if (threadIdx.x == 0) s_d0 = min(end - beg, MAXD);
    if (q == 0) s_node[grp] = node;

    float hs[8];
#pragma unroll
    for (int j = 0; j < 8; ++j) hs[j] = 0.f;

#define QACC(a) { \
    v2f p0 = __builtin_amdgcn_cvt_pk_f32_fp8((a).x, false); \
    v2f p1 = __builtin_amdgcn_cvt_pk_f32_fp8((a).x, true); \
    v2f p2 = __builtin_amdgcn_cvt_pk_f32_fp8((a).y, false); \
    v2f p3 = __builtin_amdgcn_cvt_pk_f32_fp8((a).y, true); \
    hs[0] += p0.x; hs[1] += p0.y; hs[2] += p1.x; hs[3] += p1.y; \
    hs[4] += p2.x; hs[5] += p2.y; hs[6] += p3.x; hs[7] += p3.y; }

    int e = beg;
    for (; e + 8 <= end; e += 8) {
        int s0 = csr[e + 0], s1 = csr[e + 1], s2 = csr[e + 2], s3 = csr[e + 3];
        int s4 = csr[e + 4], s5 = csr[e + 5], s6 = csr[e + 6], s7 = csr[e + 7];
        uint2 a0 = *reinterpret_cast<const uint2*>(xq + (size_t)s0 * DIM + q * 8);
        uint2 a1 = *reinterpret_cast<const uint2*>(xq + (size_t)s1 * DIM + q * 8);
        uint2 a2 = *reinterpret_cast<const uint2*>(xq + (size_t)s2 * DIM + q * 8);
        uint2 a3 = *reinterpret_cast<const uint2*>(xq + (size_t)s3 * DIM + q * 8);
        uint2 a4 = *reinterpret_cast<const uint2*>(xq + (size_t)s4 * DIM + q * 8);
        uint2 a5 = *reinterpret_cast<const uint2*>(xq + (size_t)s5 * DIM + q * 8);
        uint2 a6 = *reinterpret_cast<const uint2*>(xq + (size_t)s6 * DIM + q * 8);
        uint2 a7 = *reinterpret_cast<const uint2*>(xq + (size_t)s7 * DIM + q * 8);
        QACC(a0) QACC(a1) QACC(a2) QACC(a3)
        QACC(a4) QACC(a5) QACC(a6) QACC(a7)
    }
    for (; e + 4 <= end; e += 4) {
        int s0 = csr[e + 0], s1 = csr[e + 1], s2 = csr[e + 2], s3 = csr[e + 3];
        uint2 a0 = *reinterpret_cast<const uint2*>(xq + (size_t)s0 * DIM + q * 8);
        uint2 a1 = *reinterpret_cast<const uint2*>(xq + (size_t)s1 * DIM + q * 8);
        uint2 a2 = *reinterpret_cast<const uint2*>(xq + (size_t)s2 * DIM + q * 8);
        uint2 a3 = *reinterpret_cast<const uint2*>(xq + (size_t)s3 * DIM + q * 8);
        QACC(a0) QACC(a1) QACC(a2) QACC(a3)
    }
    for (; e < end; ++e) {
        int s = csr[e];
        uint2 a = *reinterpret_cast<const uint2*>(xq + (size_t)s * DIM + q * 8);
        QACC(a)
    }
#undef QACC

    float xv[8];
    if (valid) {
        uint2 a = *reinterpret_cast<const uint2*>(xq + (size_t)node * DIM + q * 8);
        v2f p0 = __builtin_amdgcn_cvt_pk_f32_fp8(a.x, false);
        v2f p1 = __builtin_amdgcn_cvt_pk_f32_fp8(a.x, true);
        v2f p2 = __builtin_amdgcn_cvt_pk_f32_fp8(a.y, false);
        v2f p3 = __builtin_amdgcn_cvt_pk_f32_fp8(a.y, true);
        xv[0] = p0.x; xv[1] = p0.y; xv[2] = p1.x; xv[3] = p1.y;
        xv[4] = p2.x; xv[5] = p2.y; xv[6] = p3.x; xv[7] = p3.y;
    } else {
#pragma unroll
        for (int j = 0; j < 8; ++j) xv[j] = 0.f;
    }

    *reinterpret_cast<float4*>(&lds_h[grp][q * 8 + 0]) = make_float4(hs[0], hs[1], hs[2], hs[3]);
    *reinterpret_cast<float4*>(&lds_h[grp][q * 8 + 4]) = make_float4(hs[4], hs[5], hs[6], hs[7]);
    *reinterpret_cast<float4*>(&lds_x[grp][q * 8 + 0]) = make_float4(xv[0], xv[1], xv[2], xv[3]);
    *reinterpret_cast<float4*>(&lds_x[grp][q * 8 + 4]) = make_float4(xv[4], xv[5], xv[6], xv[7]);
    __syncthreads();

    int mgrp = threadIdx.x >> 4;
    int mq   = threadIdx.x & 15;
    int d0 = s_d0;
    const float* wl = Wl + (size_t)d0 * DIM * DIM + mq * 4;
    const float* wr = Wr + (size_t)d0 * DIM * DIM + mq * 4;
    float4 accA = *reinterpret_cast<const float4*>(bl + d0 * DIM + mq * 4);
    float4 accB = accA;

#pragma unroll 8
    for (int i = 0; i < DIM; ++i) {
        float4 wlv = *reinterpret_cast<const float4*>(wl + i * DIM);
        float4 wrv = *reinterpret_cast<const float4*>(wr + i * DIM);
        float hA = lds_h[mgrp][i],      xA = lds_x[mgrp][i];
        float hB = lds_h[mgrp + 16][i], xB = lds_x[mgrp + 16][i];
        accA.x += hA * wlv.x + xA * wrv.x;
        accA.y += hA * wlv.y + xA * wrv.y;
        accA.z += hA * wlv.z + xA * wrv.z;
        accA.w += hA * wlv.w + xA * wrv.w;
        accB.x += hB * wlv.x + xB * wrv.x;
        accB.y += hB * wlv.y + xB * wrv.y;
        accB.z += hB * wlv.z + xB * wrv.z;
        accB.w += hB * wlv.w + xB * wrv.w;
    }

    int nodeA = s_node[mgrp];
    int nodeB = s_node[mgrp + 16];
    if (OUTMODE == 0) {
        if (nodeA >= 0)
            *reinterpret_cast<float4*>(outf + (size_t)nodeA * DIM + mq * 4) = accA;
        if (nodeB >= 0)
            *reinterpret_cast<float4*>(outf + (size_t)nodeB * DIM + mq * 4) = accB;
    } else {
        if (nodeA >= 0) {
            int oq = __builtin_amdgcn_cvt_pk_fp8_f32(fmaxf(accA.x, 0.f), fmaxf(accA.y, 0.f), 0, false);
            oq = __builtin_amdgcn_cvt_pk_fp8_f32(fmaxf(accA.z, 0.f), fmaxf(accA.w, 0.f), oq, true);
            *reinterpret_cast<unsigned*>(outq + (size_t)nodeA * DIM + mq * 4) = (unsigned)oq;
        }
        if (nodeB >= 0) {
            int oq = __builtin_amdgcn_cvt_pk_fp8_f32(fmaxf(accB.x, 0.f), fmaxf(accB.y, 0.f), 0, false);
            oq = __builtin_amdgcn_cvt_pk_fp8_f32(fmaxf(accB.z, 0.f), fmaxf(accB.w, 0.f), oq, true);
            *reinterpret_cast<unsigned*>(outq + (size_t)nodeB * DIM + mq * 4) = (unsigned)oq;
        }
    }
}

// ---------------------------------------------------------------------------
// Fused global_add_pool(relu(emb)) + MLP head; one block per graph.
// ---------------------------------------------------------------------------
__global__ void pool_head_kernel(const float* __restrict__ emb,
                                 const int* __restrict__ batch,
                                 const float* __restrict__ W1,
                                 const float* __restrict__ b1,
                                 const float* __restrict__ W2,
                                 const float* __restrict__ b2,
                                 float* __restrict__ pred) {
    __shared__ float red[4][DIM];
    __shared__ float garr[DIM];
    __shared__ float hid[DIM];
    int gi = blockIdx.x;
    int w = threadIdx.x >> 6;
    int lane = threadIdx.x & 63;

    int lo = 0, hi = N_NODES;
    while (lo < hi) { int mid = (lo + hi) >> 1; if (batch[mid] < gi) lo = mid + 1; else hi = mid; }
    int beg = lo;
    hi = N_NODES;
    while (lo < hi) { int mid = (lo + hi) >> 1; if (batch[mid] < gi + 1) lo = mid + 1; else hi = mid; }
    int end = lo;

    float acc = 0.f;
    for (int n = beg + w; n < end; n += 4)
        acc += fmaxf(emb[(size_t)n * DIM + lane], 0.f);
    red[w][lane] = acc;
    __syncthreads();
    if (w == 0)
        garr[lane] = red[0][lane] + red[1][lane] + red[2][lane] + red[3][lane];
    __syncthreads();

    if (threadIdx.x < DIM) {
        int o = threadIdx.x;
        float a = b1[o];
#pragma unroll 8
        for (int i = 0; i < DIM; ++i) a += garr[i] * W1[i * DIM + o];
        hid[o] = a;
    }
    __syncthreads();
    if (threadIdx.x < ODIM) {
        int o = threadIdx.x;
        float p = b2[o];
#pragma unroll 8
        for (int i = 0; i < DIM; ++i) p += hid[i] * W2[i * ODIM + o];
        pred[(size_t)gi * ODIM + o] = p;
    }
}

extern "C" void kernel_launch(void* const* d_in, const int* in_sizes, int n_in,
                              void* d_out, int out_size, void* d_ws, size_t ws_size,
                              hipStream_t stream) {
    const float* x    = (const float*)d_in[0];
    const int* eidx   = (const int*)d_in[1];
    const int* src    = eidx;
    const int* dst    = eidx + N_EDGES;
    const int* batch  = (const int*)d_in[2];
    const float* Wl1  = (const float*)d_in[4];
    const float* bl1  = (const float*)d_in[5];
    const float* Wr1  = (const float*)d_in[6];
    const float* Wl2  = (const float*)d_in[7];
    const float* bl2  = (const float*)d_in[8];
    const float* Wr2  = (const float*)d_in[9];
    const float* W1   = (const float*)d_in[10];
    const float* b1   = (const float*)d_in[11];
    const float* W2   = (const float*)d_in[12];
    const float* b2   = (const float*)d_in[13];

    float* emb  = (float*)d_out;                          // [N_NODES, 64]
    float* pred = (float*)d_out + (size_t)N_NODES * DIM;  // [N_GRAPHS, 32]

    // Workspace
    int* bcur     = (int*)d_ws;                  // [256]
    int* ebase    = bcur + 256;                  // [256]
    int* gcount   = ebase + 256;                 // [32]
    int* gcur     = gcount + NBKT;               // [32]
    int* deg      = gcur + NBKT;                 // [100000]
    int* rowptr   = deg + N_NODES;               // [100004]
    int* nodelist = rowptr + N_NODES + 4;        // [100992]
    int* csr      = nodelist + LIST_PAD;         // [1200000]
    int* pairs    = csr + N_EDGES;               // [196*8192]
    unsigned char* xq = (unsigned char*)(pairs + NBUK * CAP);    // [N*64] fp8
    unsigned char* hq = xq + (size_t)N_NODES * DIM;              // [N*64] fp8

    prep_kernel<<<(PREP_THREADS + 255) / 256, 256, 0, stream>>>(x, xq, bcur, gcount, nodelist);
    pass1_bin_kernel<<<P1_NB, 256, 0, stream>>>(src, dst, bcur, pairs);
    escan_kernel<<<1, 256, 0, stream>>>(bcur, ebase, rowptr);
    pass2_kernel<<<NBUK, 256, 0, stream>>>(pairs, bcur, ebase, deg, rowptr, csr, gcount);
    gscan_kernel<<<1, 64, 0, stream>>>(gcount, gcur);
    bucket_scatter_kernel<<<(N_NODES + 255) / 256, 256, 0, stream>>>(deg, gcur, nodelist);

    // conv1: fp8 gather + matvec + relu -> hq (fp8 table for conv2)
    conv_fp8_kernel<1><<<CONV_BLK, 256, 0, stream>>>(xq, rowptr, csr, nodelist,
                                                     Wl1, bl1, Wr1, nullptr, hq);
    // conv2: fp8 gather + matvec -> emb (f32, pre-activation output)
    conv_fp8_kernel<0><<<CONV_BLK, 256, 0, stream>>>(hq, rowptr, csr, nodelist,
                                                     Wl2, bl2, Wr2, emb, nullptr);
    // fused pool + head
    pool_head_kernel<<<N_GRAPHS, 256, 0, stream>>>(emb, batch, W1, b1, W2, b2, pred);
}